// Round 1
// baseline (14143.700 us; speedup 1.0000x reference)
//
#include <hip/hip_runtime.h>
#include <math.h>

#define NTOT 6144
#define UU   3072
#define II   3072
#define DD   128
#define SS   3072
#define DFF2 512
#define HH   4

// ---------------- sinusoidal PE table ----------------
__global__ void pe_k(float* __restrict__ pe) {
  int idx = blockIdx.x * 256 + threadIdx.x;
  if (idx >= NTOT * 64) return;
  int pos = idx >> 6, j = idx & 63;
  float ex = (2.0f * (float)j) * (-0.07195578415606394f);  // -ln(10000)/128
  float dv = expf(ex);
  float ang = (float)pos * dv;
  pe[(size_t)pos * DD + 2 * j]     = sinf(ang);
  pe[(size_t)pos * DD + 2 * j + 1] = cosf(ang);
}

// ---------------- dinv = (rowsum(vs)+eps)^-0.5 ----------------
__global__ void dinv_k(const float* __restrict__ vs, float* __restrict__ dinv) {
  int i = blockIdx.x, tid = threadIdx.x;
  __shared__ float red[256];
  float s = 0.f;
  const float* row = vs + (size_t)i * II;
  for (int j = tid; j < II; j += 256) s += row[j];
  red[tid] = s; __syncthreads();
  for (int st = 128; st > 0; st >>= 1) { if (tid < st) red[tid] += red[tid + st]; __syncthreads(); }
  if (tid == 0) dinv[i] = 1.0f / sqrtf(red[0] + 1e-7f);
}

// ---------------- generic tiled fp32 GEMM ----------------
// C = [ACC? C:0/=] + rowscale[i]*scale*(A@B) + bias[j], optional relu
template<bool RELU, bool ACC>
__global__ void gemm_k(const float* __restrict__ A, const float* __restrict__ B,
                       const float* __restrict__ bias, const float* __restrict__ rowscale,
                       const float* __restrict__ scale_ptr, float* __restrict__ C,
                       int M, int N, int K) {
  __shared__ float As[16][65];   // A tile transposed, padded (bank-conflict-free)
  __shared__ float Bs[16][64];
  const int tid = threadIdx.x;
  const int tx = tid & 15, ty = tid >> 4;
  const int bm = blockIdx.y * 64, bn = blockIdx.x * 64;
  float acc[4][4] = {{0.f}};
  for (int k0 = 0; k0 < K; k0 += 16) {
    for (int l = tid; l < 1024; l += 256) {
      int m = l >> 4, kk = l & 15;
      int row = bm + m;
      As[kk][m] = (row < M) ? A[(size_t)row * K + k0 + kk] : 0.0f;
    }
    for (int l = tid; l < 1024; l += 256) {
      int kk = l >> 6, n = l & 63;
      int col = bn + n;
      Bs[kk][n] = (col < N) ? B[(size_t)(k0 + kk) * N + col] : 0.0f;
    }
    __syncthreads();
#pragma unroll
    for (int kk = 0; kk < 16; ++kk) {
      float a[4], b[4];
#pragma unroll
      for (int i = 0; i < 4; ++i) a[i] = As[kk][ty * 4 + i];
#pragma unroll
      for (int j = 0; j < 4; ++j) b[j] = Bs[kk][tx * 4 + j];
#pragma unroll
      for (int i = 0; i < 4; ++i)
#pragma unroll
        for (int j = 0; j < 4; ++j)
          acc[i][j] = fmaf(a[i], b[j], acc[i][j]);
    }
    __syncthreads();
  }
  float sc = scale_ptr ? scale_ptr[0] : 1.0f;
#pragma unroll
  for (int i = 0; i < 4; ++i) {
    int row = bm + ty * 4 + i;
    if (row >= M) continue;
    float rs = rowscale ? rowscale[row] * sc : sc;
#pragma unroll
    for (int j = 0; j < 4; ++j) {
      int col = bn + tx * 4 + j;
      if (col >= N) continue;
      float v = acc[i][j] * rs + (bias ? bias[col] : 0.0f);
      if (RELU) v = fmaxf(v, 0.0f);
      size_t o = (size_t)row * N + col;
      if (ACC) C[o] += v; else C[o] = v;
    }
  }
}

// ---------------- fused top-K(10) score + masked SpMM ----------------
// one block per row i: scores = 0.5*E[i]·E[j] + 0.5*adj[i,j]; pick top-10
// (ties -> lower index, matching jax.lax.top_k); cur[i] = sum adj[i,idx]*E[idx]
__global__ void topk_spmm_k(const float* __restrict__ E, const float* __restrict__ adj,
                            float* __restrict__ cur) {
  int i = blockIdx.x, tid = threadIdx.x;
  __shared__ float sc[NTOT];           // 24 KB
  __shared__ alignas(16) float ei[DD];
  __shared__ float rv[256];
  __shared__ int   ri[256];
  if (tid < DD) ei[tid] = E[(size_t)i * DD + tid];
  __syncthreads();
  const float* arow = adj + (size_t)i * NTOT;
  const float4* e4 = (const float4*)ei;
  for (int j = tid; j < NTOT; j += 256) {
    const float4* er = (const float4*)(E + (size_t)j * DD);
    float d = 0.f;
#pragma unroll
    for (int t = 0; t < 32; ++t) {
      float4 a = e4[t], b = er[t];
      d += a.x * b.x + a.y * b.y + a.z * b.z + a.w * b.w;
    }
    sc[j] = 0.5f * d + 0.5f * arow[j];
  }
  __syncthreads();
  float racc = 0.f;
  for (int it = 0; it < 10; ++it) {
    float bv = -INFINITY; int bi = 0x7fffffff;
    for (int j = tid; j < NTOT; j += 256) {
      float v = sc[j];
      if (v > bv) { bv = v; bi = j; }   // ascending scan keeps lowest index on ties
    }
    rv[tid] = bv; ri[tid] = bi; __syncthreads();
    for (int st = 128; st > 0; st >>= 1) {
      if (tid < st) {
        float v2 = rv[tid + st]; int i2 = ri[tid + st];
        if (v2 > rv[tid] || (v2 == rv[tid] && i2 < ri[tid])) { rv[tid] = v2; ri[tid] = i2; }
      }
      __syncthreads();
    }
    int midx = ri[0];
    float aval = arow[midx];
    if (tid < DD && aval != 0.f) racc += aval * E[(size_t)midx * DD + tid];
    if (tid == 0) sc[midx] = -INFINITY;
    __syncthreads();
  }
  if (tid < DD) cur[(size_t)i * DD + tid] = racc;
}

// ---------------- elementwise helpers ----------------
__global__ void blend_k(const float* __restrict__ rawp, const float* __restrict__ ue,
                        const float* __restrict__ ie, const float* __restrict__ alpha_p,
                        float* __restrict__ x0) {
  int idx = blockIdx.x * 256 + threadIdx.x;
  if (idx >= NTOT * DD) return;
  float a = alpha_p[0];
  float learned = (idx < UU * DD) ? ue[idx] : ie[idx - UU * DD];
  x0[idx] = a * rawp[idx] + (1.0f - a) * learned;
}

__global__ void scale_rows_k(const float* __restrict__ prevI, const float* __restrict__ dinv,
                             float* __restrict__ ps) {
  int idx = blockIdx.x * 256 + threadIdx.x;
  if (idx >= II * DD) return;
  ps[idx] = dinv[idx >> 7] * prevI[idx];
}

__global__ void gate_pe_k(float* __restrict__ cur, const float* __restrict__ tmp,
                          const float* __restrict__ pe) {
  int idx = blockIdx.x * 256 + threadIdx.x;
  if (idx >= NTOT * DD) return;
  float g = 1.0f / (1.0f + expf(-tmp[idx]));
  cur[idx] += g * pe[idx];
}

__global__ void final_k(const float* __restrict__ x0, const float* __restrict__ x1,
                        const float* __restrict__ x2, float* __restrict__ out) {
  int idx = blockIdx.x * 256 + threadIdx.x;
  if (idx >= NTOT * DD) return;
  float v = x0[idx] + 0.75f * x1[idx] + 0.5f * x2[idx];
  out[idx] = v;
  out[NTOT * DD + idx] = v;   // (final[:U], final[U:]) concatenated == final
}

// ---------------- fused attention (one block per (row, head)) ----------------
__global__ void attn_k(const float* __restrict__ Q, const float* __restrict__ Km,
                       const float* __restrict__ V, float* __restrict__ O) {
  int s = blockIdx.x, h = blockIdx.y, tid = threadIdx.x;
  int hoff = h * 32;
  __shared__ float scs[SS];             // 12 KB
  __shared__ alignas(16) float qs[32];
  __shared__ float red[256];
  if (tid < 32) qs[tid] = Q[(size_t)s * DD + hoff + tid];
  __syncthreads();
  const float4* q4 = (const float4*)qs;
  float lmax = -INFINITY;
  for (int j = tid; j < SS; j += 256) {
    const float4* kr = (const float4*)(Km + (size_t)j * DD + hoff);
    float d = 0.f;
#pragma unroll
    for (int t = 0; t < 8; ++t) {
      float4 a = q4[t], b = kr[t];
      d += a.x * b.x + a.y * b.y + a.z * b.z + a.w * b.w;
    }
    d *= 0.17677669529663687f;  // 1/sqrt(32)
    scs[j] = d;
    lmax = fmaxf(lmax, d);
  }
  red[tid] = lmax; __syncthreads();
  for (int st = 128; st > 0; st >>= 1) { if (tid < st) red[tid] = fmaxf(red[tid], red[tid + st]); __syncthreads(); }
  float m = red[0]; __syncthreads();
  float lsum = 0.f;
  for (int j = tid; j < SS; j += 256) { float p = expf(scs[j] - m); scs[j] = p; lsum += p; }
  red[tid] = lsum; __syncthreads();
  for (int st = 128; st > 0; st >>= 1) { if (tid < st) red[tid] += red[tid + st]; __syncthreads(); }
  float denom = red[0]; __syncthreads();
  int d = tid & 31, c = tid >> 5;            // 8 chunks of 384
  float acc = 0.f;
  int j0 = c * (SS / 8), j1 = j0 + (SS / 8);
  for (int j = j0; j < j1; ++j) acc += scs[j] * V[(size_t)j * DD + hoff + d];
  red[tid] = acc; __syncthreads();
  if (tid < 32) {
    float o = 0.f;
#pragma unroll
    for (int cc = 0; cc < 8; ++cc) o += red[cc * 32 + tid];
    O[(size_t)s * DD + hoff + tid] = o / denom;
  }
}

// ---------------- residual + LayerNorm (one block of 128 per row) ----------------
__global__ void add_ln_k(const float* __restrict__ X, const float* __restrict__ Y,
                         const float* __restrict__ g, const float* __restrict__ b,
                         float* __restrict__ Out) {
  int row = blockIdx.x, tid = threadIdx.x;
  __shared__ float red[128];
  float v = X[(size_t)row * DD + tid] + Y[(size_t)row * DD + tid];
  red[tid] = v; __syncthreads();
  for (int st = 64; st > 0; st >>= 1) { if (tid < st) red[tid] += red[tid + st]; __syncthreads(); }
  float mean = red[0] * (1.0f / DD); __syncthreads();
  float d = v - mean;
  red[tid] = d * d; __syncthreads();
  for (int st = 64; st > 0; st >>= 1) { if (tid < st) red[tid] += red[tid + st]; __syncthreads(); }
  float var = red[0] * (1.0f / DD); __syncthreads();
  Out[(size_t)row * DD + tid] = d * (1.0f / sqrtf(var + 1e-5f)) * g[tid] + b[tid];
}

// ---------------- host-side helpers ----------------
static inline void gemm(const float* A, const float* B, const float* bias,
                        const float* rowscale, const float* scale_ptr, float* C,
                        int M, int N, int K, bool relu, bool acc, hipStream_t s) {
  dim3 g((N + 63) / 64, (M + 63) / 64), b(256);
  if (acc)       gemm_k<false, true ><<<g, b, 0, s>>>(A, B, bias, rowscale, scale_ptr, C, M, N, K);
  else if (relu) gemm_k<true,  false><<<g, b, 0, s>>>(A, B, bias, rowscale, scale_ptr, C, M, N, K);
  else           gemm_k<false, false><<<g, b, 0, s>>>(A, B, bias, rowscale, scale_ptr, C, M, N, K);
}

static void encoder(const float* xin, float* xout,
                    const float* aw, const float* ab,
                    const float* w1, const float* b1,
                    const float* w2, const float* b2,
                    const float* lng, const float* lnb,
                    float* q, float* kb, float* vb, float* ao, float* xl,
                    float* t1, float* f2, hipStream_t s) {
  gemm(xin, aw + 0 * DD * DD, ab + 0 * DD, nullptr, nullptr, q,  SS, DD, DD, false, false, s);
  gemm(xin, aw + 1 * DD * DD, ab + 1 * DD, nullptr, nullptr, kb, SS, DD, DD, false, false, s);
  gemm(xin, aw + 2 * DD * DD, ab + 2 * DD, nullptr, nullptr, vb, SS, DD, DD, false, false, s);
  attn_k<<<dim3(SS, HH), 256, 0, s>>>(q, kb, vb, ao);
  gemm(ao, aw + 3 * DD * DD, ab + 3 * DD, nullptr, nullptr, f2, SS, DD, DD, false, false, s);
  add_ln_k<<<SS, 128, 0, s>>>(xin, f2, lng, lnb, xl);
  gemm(xl, w1, b1, nullptr, nullptr, t1, SS, DFF2, DD, true,  false, s);
  gemm(t1, w2, b2, nullptr, nullptr, f2, SS, DD, DFF2, false, false, s);
  add_ln_k<<<SS, 128, 0, s>>>(xl, f2, lng + DD, lnb + DD, xout);
}

extern "C" void kernel_launch(void* const* d_in, const int* in_sizes, int n_in,
                              void* d_out, int out_size, void* d_ws, size_t ws_size,
                              hipStream_t stream) {
  (void)in_sizes; (void)n_in; (void)out_size; (void)ws_size;
  const float* adj       = (const float*)d_in[0];
  const float* raw_nodes = (const float*)d_in[1];
  const float* proj_w    = (const float*)d_in[2];
  const float* proj_b    = (const float*)d_in[3];
  const float* user_emb  = (const float*)d_in[4];
  const float* item_emb  = (const float*)d_in[5];
  const float* vs        = (const float*)d_in[6];
  const float* alpha_p   = (const float*)d_in[7];
  const float* pgw       = (const float*)d_in[8];
  const float* pgb       = (const float*)d_in[9];
  const float* uaw = (const float*)d_in[10];
  const float* uab = (const float*)d_in[11];
  const float* uw1 = (const float*)d_in[12];
  const float* ub1 = (const float*)d_in[13];
  const float* uw2 = (const float*)d_in[14];
  const float* ub2 = (const float*)d_in[15];
  const float* ulg = (const float*)d_in[16];
  const float* ulb = (const float*)d_in[17];
  const float* iaw = (const float*)d_in[18];
  const float* iab = (const float*)d_in[19];
  const float* iw1 = (const float*)d_in[20];
  const float* ib1 = (const float*)d_in[21];
  const float* iw2 = (const float*)d_in[22];
  const float* ib2 = (const float*)d_in[23];
  const float* ilg = (const float*)d_in[24];
  const float* ilb = (const float*)d_in[25];

  float* w = (float*)d_ws;
  float* pe   = w; w += (size_t)NTOT * DD;
  float* x0   = w; w += (size_t)NTOT * DD;
  float* x1   = w; w += (size_t)NTOT * DD;
  float* x2   = w; w += (size_t)NTOT * DD;
  float* cur  = w; w += (size_t)NTOT * DD;
  float* tmp1 = w; w += (size_t)NTOT * DD;
  float* q    = w; w += (size_t)SS * DD;
  float* kb   = w; w += (size_t)SS * DD;
  float* vb   = w; w += (size_t)SS * DD;
  float* ao   = w; w += (size_t)SS * DD;
  float* xl   = w; w += (size_t)SS * DD;
  float* f2   = w; w += (size_t)SS * DD;
  float* t1   = w; w += (size_t)SS * DFF2;
  float* ps   = w; w += (size_t)II * DD;
  float* dinv = w; w += 4096;

  pe_k<<<(NTOT * 64 + 255) / 256, 256, 0, stream>>>(pe);
  dinv_k<<<II, 256, 0, stream>>>(vs, dinv);
  gemm(raw_nodes, proj_w, proj_b, nullptr, nullptr, tmp1, NTOT, DD, 1280, false, false, stream);
  blend_k<<<(NTOT * DD + 255) / 256, 256, 0, stream>>>(tmp1, user_emb, item_emb, alpha_p, x0);

  float* xs[3] = {x0, x1, x2};
  for (int b = 0; b < 2; ++b) {
    const float* prev = xs[b];
    float* outb = xs[b + 1];
    topk_spmm_k<<<NTOT, 256, 0, stream>>>(prev, adj, cur);
    scale_rows_k<<<(II * DD + 255) / 256, 256, 0, stream>>>(prev + (size_t)UU * DD, dinv, ps);
    // cur[U:] += alpha * dinv_i * (vs @ (dinv_j * prev[U:]))
    gemm(vs, ps, nullptr, dinv, alpha_p, cur + (size_t)UU * DD, II, DD, II, false, true, stream);
    gemm(cur, pgw, pgb, nullptr, nullptr, tmp1, NTOT, DD, DD, false, false, stream);
    gate_pe_k<<<(NTOT * DD + 255) / 256, 256, 0, stream>>>(cur, tmp1, pe);
    encoder(cur,                   outb,                   uaw, uab, uw1, ub1, uw2, ub2, ulg, ulb,
            q, kb, vb, ao, xl, t1, f2, stream);
    encoder(cur + (size_t)UU * DD, outb + (size_t)UU * DD, iaw, iab, iw1, ib1, iw2, ib2, ilg, ilb,
            q, kb, vb, ao, xl, t1, f2, stream);
  }
  final_k<<<(NTOT * DD + 255) / 256, 256, 0, stream>>>(x0, x1, x2, (float*)d_out);
}

// Round 3
// 5053.937 us; speedup vs baseline: 2.7986x; 2.7986x over previous
//
#include <hip/hip_runtime.h>
#include <math.h>

#define NTOT 6144
#define UU   3072
#define II   3072
#define DD   128
#define SS   3072
#define DFF2 512
#define HH   4

// ---------------- sinusoidal PE table ----------------
__global__ void pe_k(float* __restrict__ pe) {
  int idx = blockIdx.x * 256 + threadIdx.x;
  if (idx >= NTOT * 64) return;
  int pos = idx >> 6, j = idx & 63;
  float ex = (2.0f * (float)j) * (-0.07195578415606394f);  // -ln(10000)/128
  float dv = expf(ex);
  float ang = (float)pos * dv;
  pe[(size_t)pos * DD + 2 * j]     = sinf(ang);
  pe[(size_t)pos * DD + 2 * j + 1] = cosf(ang);
}

// ---------------- dinv = (rowsum(vs)+eps)^-0.5 ----------------
__global__ void dinv_k(const float* __restrict__ vs, float* __restrict__ dinv) {
  int i = blockIdx.x, tid = threadIdx.x;
  __shared__ float red[256];
  float s = 0.f;
  const float* row = vs + (size_t)i * II;
  for (int j = tid; j < II; j += 256) s += row[j];
  red[tid] = s; __syncthreads();
  for (int st = 128; st > 0; st >>= 1) { if (tid < st) red[tid] += red[tid + st]; __syncthreads(); }
  if (tid == 0) dinv[i] = 1.0f / sqrtf(red[0] + 1e-7f);
}

// ---------------- generic tiled fp32 GEMM ----------------
template<bool RELU, bool ACC>
__global__ __launch_bounds__(256) void gemm_k(
    const float* __restrict__ A, const float* __restrict__ B,
    const float* __restrict__ bias, const float* __restrict__ rowscale,
    const float* __restrict__ scale_ptr, float* __restrict__ C,
    int M, int N, int K) {
  __shared__ float As[16][65];
  __shared__ float Bs[16][64];
  const int tid = threadIdx.x;
  const int tx = tid & 15, ty = tid >> 4;
  const int bm = blockIdx.y * 64, bn = blockIdx.x * 64;
  float acc[4][4] = {{0.f}};
  for (int k0 = 0; k0 < K; k0 += 16) {
    for (int l = tid; l < 1024; l += 256) {
      int m = l >> 4, kk = l & 15;
      int row = bm + m;
      As[kk][m] = (row < M) ? A[(size_t)row * K + k0 + kk] : 0.0f;
    }
    for (int l = tid; l < 1024; l += 256) {
      int kk = l >> 6, n = l & 63;
      int col = bn + n;
      Bs[kk][n] = (col < N) ? B[(size_t)(k0 + kk) * N + col] : 0.0f;
    }
    __syncthreads();
#pragma unroll
    for (int kk = 0; kk < 16; ++kk) {
      float a[4], b[4];
#pragma unroll
      for (int i = 0; i < 4; ++i) a[i] = As[kk][ty * 4 + i];
#pragma unroll
      for (int j = 0; j < 4; ++j) b[j] = Bs[kk][tx * 4 + j];
#pragma unroll
      for (int i = 0; i < 4; ++i)
#pragma unroll
        for (int j = 0; j < 4; ++j)
          acc[i][j] = fmaf(a[i], b[j], acc[i][j]);
    }
    __syncthreads();
  }
  float sc = scale_ptr ? scale_ptr[0] : 1.0f;
#pragma unroll
  for (int i = 0; i < 4; ++i) {
    int row = bm + ty * 4 + i;
    if (row >= M) continue;
    float rs = rowscale ? rowscale[row] * sc : sc;
#pragma unroll
    for (int j = 0; j < 4; ++j) {
      int col = bn + tx * 4 + j;
      if (col >= N) continue;
      float v = acc[i][j] * rs + (bias ? bias[col] : 0.0f);
      if (RELU) v = fmaxf(v, 0.0f);
      size_t o = (size_t)row * N + col;
      if (ACC) C[o] += v; else C[o] = v;
    }
  }
}

// ---------------- top-10 register list insertion (descending, ties -> lower idx) ----
__device__ __forceinline__ void ins10(float (&v)[10], int (&ix)[10], float cv, int ci) {
  if (!((cv > v[9]) || (cv == v[9] && ci < ix[9]))) return;  // quick reject vs current min
#pragma unroll
  for (int q = 0; q < 10; ++q) {
    bool b = (cv > v[q]) || (cv == v[q] && ci < ix[q]);
    float ov = v[q]; int oi = ix[q];
    if (b) { v[q] = cv; ix[q] = ci; cv = ov; ci = oi; }
  }
}

// ---------------- top-K partial: per (j-half, 32-row tile) -----------------
__global__ __launch_bounds__(256) void topk_part_k(
    const float* __restrict__ E, const float* __restrict__ adj,
    float* __restrict__ topv, int* __restrict__ topi) {
  const int half = blockIdx.x;         // 0/1
  const int i0 = blockIdx.y * 32;
  const int jb = half * 3072;
  const int tid = threadIdx.x;
  const int a0 = tid & 15;             // i-group: rows a0, a0+16
  const int b0 = tid >> 4;             // j-group: cols b0+16u

  __shared__ __align__(16) unsigned char sm[59008];
  float4* Ei4  = (float4*)sm;                 // 32*33 f4  = 16896 B
  float4* Ej4  = (float4*)(sm + 16896);       // 64*33 f4  = 33792 B
  float*  adjt = (float*)(sm + 50688);        // 32*65 f   =  8320 B
  // post-loop overlays (regions dead after candidate loop):
  float* dv   = (float*)(sm + 16896);         // 32*16*10 f = 20480
  int*   di   = (int*)  (sm + 37376);         // 20480
  float* redv = (float*)(sm + 0);             // 32*16 f
  int*   redi = (int*)  (sm + 2048);
  float* wlv  = (float*)(sm + 4096);          // 32*10 f
  int*   wli  = (int*)  (sm + 5376);

  for (int p = 0; p < 4; ++p) {
    int l = tid + p * 256, r = l >> 5, c = l & 31;
    Ei4[r * 33 + c] = ((const float4*)(E + (size_t)(i0 + r) * DD))[c];
  }

  float v0[10], v1[10]; int x0i[10], x1i[10];
#pragma unroll
  for (int q = 0; q < 10; ++q) { v0[q] = -INFINITY; v1[q] = -INFINITY; x0i[q] = 0x7fffffff; x1i[q] = 0x7fffffff; }

  for (int jt = 0; jt < 48; ++jt) {
    const int jc = jb + jt * 64;
    __syncthreads();
    for (int p = 0; p < 8; ++p) {
      int l = tid + p * 256, r = l >> 5, c = l & 31;
      Ej4[r * 33 + c] = ((const float4*)(E + (size_t)(jc + r) * DD))[c];
    }
    for (int p = 0; p < 8; ++p) {
      int l = tid + p * 256, r = l >> 6, c = l & 63;
      adjt[r * 65 + c] = adj[(size_t)(i0 + r) * NTOT + jc + c];
    }
    __syncthreads();

    float d0[4] = {0.f, 0.f, 0.f, 0.f}, d1[4] = {0.f, 0.f, 0.f, 0.f};
#pragma unroll 4
    for (int kq = 0; kq < 32; ++kq) {
      float4 aa = Ei4[a0 * 33 + kq];
      float4 ab = Ei4[(a0 + 16) * 33 + kq];
#pragma unroll
      for (int u = 0; u < 4; ++u) {
        float4 b = Ej4[(b0 + 16 * u) * 33 + kq];
        d0[u] = fmaf(aa.x, b.x, fmaf(aa.y, b.y, fmaf(aa.z, b.z, fmaf(aa.w, b.w, d0[u]))));
        d1[u] = fmaf(ab.x, b.x, fmaf(ab.y, b.y, fmaf(ab.z, b.z, fmaf(ab.w, b.w, d1[u]))));
      }
    }
#pragma unroll
    for (int u = 0; u < 4; ++u) {
      int jl = b0 + 16 * u, jg = jc + jl;
      ins10(v0, x0i, 0.5f * d0[u] + 0.5f * adjt[a0 * 65 + jl], jg);
      ins10(v1, x1i, 0.5f * d1[u] + 0.5f * adjt[(a0 + 16) * 65 + jl], jg);
    }
  }

  __syncthreads();
  const int r0 = a0, r1 = a0 + 16;
#pragma unroll
  for (int q = 0; q < 10; ++q) {
    dv[r0 * 160 + b0 * 10 + q] = v0[q];  di[r0 * 160 + b0 * 10 + q] = x0i[q];
    dv[r1 * 160 + b0 * 10 + q] = v1[q];  di[r1 * 160 + b0 * 10 + q] = x1i[q];
  }
  __syncthreads();

  int p0 = 0, p1 = 0;
  for (int round = 0; round < 10; ++round) {
    float h0 = dv[r0 * 160 + b0 * 10 + p0]; int h0i = di[r0 * 160 + b0 * 10 + p0];
    float h1 = dv[r1 * 160 + b0 * 10 + p1]; int h1i = di[r1 * 160 + b0 * 10 + p1];
    redv[r0 * 16 + b0] = h0; redi[r0 * 16 + b0] = h0i;
    redv[r1 * 16 + b0] = h1; redi[r1 * 16 + b0] = h1i;
    __syncthreads();
    for (int st = 8; st >= 1; st >>= 1) {
      if (b0 < st) {
        float ov = redv[r0 * 16 + b0 + st]; int oi = redi[r0 * 16 + b0 + st];
        if (ov > redv[r0 * 16 + b0] || (ov == redv[r0 * 16 + b0] && oi < redi[r0 * 16 + b0])) {
          redv[r0 * 16 + b0] = ov; redi[r0 * 16 + b0] = oi;
        }
        ov = redv[r1 * 16 + b0 + st]; oi = redi[r1 * 16 + b0 + st];
        if (ov > redv[r1 * 16 + b0] || (ov == redv[r1 * 16 + b0] && oi < redi[r1 * 16 + b0])) {
          redv[r1 * 16 + b0] = ov; redi[r1 * 16 + b0] = oi;
        }
      }
      __syncthreads();
    }
    int w0 = redi[r0 * 16], w1 = redi[r1 * 16];
    if (b0 == 0) {
      wlv[r0 * 10 + round] = redv[r0 * 16]; wli[r0 * 10 + round] = w0;
      wlv[r1 * 10 + round] = redv[r1 * 16]; wli[r1 * 10 + round] = w1;
    }
    if (w0 == h0i) ++p0;
    if (w1 == h1i) ++p1;
    __syncthreads();
  }

  // BUGFIX (round 2 crash): 320 work items but only 256 threads -> stride loop.
  for (int t = tid; t < 320; t += 256) {
    int row = t / 10, q = t - row * 10;
    int gi = i0 + row;
    topv[(size_t)gi * 20 + half * 10 + q] = wlv[row * 10 + q];
    topi[(size_t)gi * 20 + half * 10 + q] = wli[row * 10 + q];
  }
}

// ---------------- merge halves + gather SpMM: cur[i] = sum adj[i,idx]*E[idx] ----
__global__ __launch_bounds__(256) void topk_merge_k(
    const float* __restrict__ topv, const int* __restrict__ topi,
    const float* __restrict__ adj, const float* __restrict__ E,
    float* __restrict__ cur) {
  const int i0 = blockIdx.x * 16, tid = threadIdx.x;
  __shared__ int   midx[16][10];
  __shared__ float madj[16][10];
  if (tid < 16) {
    int row = i0 + tid;
    const float* va = topv + (size_t)row * 20;
    const int*   ia = topi + (size_t)row * 20;
    int pa = 0, pb = 0;
    for (int q = 0; q < 10; ++q) {
      float av = va[pa], bv = va[10 + pb];
      int ai = ia[pa], bi = ia[10 + pb];
      bool ta = (av > bv) || (av == bv && ai < bi);
      int idx = ta ? ai : bi;
      if (ta) ++pa; else ++pb;
      midx[tid][q] = idx;
      madj[tid][q] = adj[(size_t)row * NTOT + idx];
    }
  }
  __syncthreads();
  int d = tid & 127, hf = tid >> 7;
  for (int rr = 0; rr < 8; ++rr) {
    int r = rr * 2 + hf;
    float acc = 0.f;
#pragma unroll
    for (int w = 0; w < 10; ++w) acc += madj[r][w] * E[(size_t)midx[r][w] * DD + d];
    cur[(size_t)(i0 + r) * DD + d] = acc;
  }
}

// ---------------- elementwise helpers ----------------
__global__ void blend_k(const float* __restrict__ rawp, const float* __restrict__ ue,
                        const float* __restrict__ ie, const float* __restrict__ alpha_p,
                        float* __restrict__ x0) {
  int idx = blockIdx.x * 256 + threadIdx.x;
  if (idx >= NTOT * DD) return;
  float a = alpha_p[0];
  float learned = (idx < UU * DD) ? ue[idx] : ie[idx - UU * DD];
  x0[idx] = a * rawp[idx] + (1.0f - a) * learned;
}

__global__ void scale_rows_k(const float* __restrict__ prevI, const float* __restrict__ dinv,
                             float* __restrict__ ps) {
  int idx = blockIdx.x * 256 + threadIdx.x;
  if (idx >= II * DD) return;
  ps[idx] = dinv[idx >> 7] * prevI[idx];
}

__global__ void gate_pe_k(float* __restrict__ cur, const float* __restrict__ tmp,
                          const float* __restrict__ pe) {
  int idx = blockIdx.x * 256 + threadIdx.x;
  if (idx >= NTOT * DD) return;
  float g = 1.0f / (1.0f + expf(-tmp[idx]));
  cur[idx] += g * pe[idx];
}

__global__ void final_k(const float* __restrict__ x0, const float* __restrict__ x1,
                        const float* __restrict__ x2, float* __restrict__ out) {
  int idx = blockIdx.x * 256 + threadIdx.x;
  if (idx >= NTOT * DD) return;
  float v = x0[idx] + 0.75f * x1[idx] + 0.5f * x2[idx];
  out[idx] = v;
  out[NTOT * DD + idx] = v;
}

// ---------------- fused attention (block per (row, head)), K staged via LDS ----
__global__ __launch_bounds__(256) void attn_k(
    const float* __restrict__ Q, const float* __restrict__ Km,
    const float* __restrict__ V, float* __restrict__ O) {
  int s = blockIdx.x, h = blockIdx.y, tid = threadIdx.x;
  int hoff = h * 32;
  __shared__ float scs[SS];             // 12 KB
  __shared__ float4 Kt[256 * 9];        // 36.9 KB (pad stride 9)
  __shared__ float4 qs4[8];
  __shared__ float red[256];
  if (tid < 8) qs4[tid] = ((const float4*)(Q + (size_t)s * DD + hoff))[tid];
  float lmax = -INFINITY;
  for (int t0 = 0; t0 < SS; t0 += 256) {
    __syncthreads();
#pragma unroll
    for (int p = 0; p < 8; ++p) {
      int l = tid + p * 256, r = l >> 3, c = l & 7;
      Kt[r * 9 + c] = ((const float4*)(Km + (size_t)(t0 + r) * DD + hoff))[c];
    }
    __syncthreads();
    float d = 0.f;
#pragma unroll
    for (int t = 0; t < 8; ++t) {
      float4 a = qs4[t], b = Kt[tid * 9 + t];
      d += a.x * b.x + a.y * b.y + a.z * b.z + a.w * b.w;
    }
    d *= 0.17677669529663687f;  // 1/sqrt(32)
    scs[t0 + tid] = d;
    lmax = fmaxf(lmax, d);
  }
  red[tid] = lmax; __syncthreads();
  for (int st = 128; st > 0; st >>= 1) { if (tid < st) red[tid] = fmaxf(red[tid], red[tid + st]); __syncthreads(); }
  float m = red[0]; __syncthreads();
  float lsum = 0.f;
  for (int j = tid; j < SS; j += 256) { float p = expf(scs[j] - m); scs[j] = p; lsum += p; }
  red[tid] = lsum; __syncthreads();
  for (int st = 128; st > 0; st >>= 1) { if (tid < st) red[tid] += red[tid + st]; __syncthreads(); }
  float denom = red[0]; __syncthreads();
  int d = tid & 31, c = tid >> 5;
  float acc = 0.f;
  int j0 = c * (SS / 8), j1 = j0 + (SS / 8);
  for (int j = j0; j < j1; ++j) acc += scs[j] * V[(size_t)j * DD + hoff + d];
  red[tid] = acc; __syncthreads();
  if (tid < 32) {
    float o = 0.f;
#pragma unroll
    for (int cc = 0; cc < 8; ++cc) o += red[cc * 32 + tid];
    O[(size_t)s * DD + hoff + tid] = o / denom;
  }
}

// ---------------- residual + LayerNorm ----------------
__global__ void add_ln_k(const float* __restrict__ X, const float* __restrict__ Y,
                         const float* __restrict__ g, const float* __restrict__ b,
                         float* __restrict__ Out) {
  int row = blockIdx.x, tid = threadIdx.x;
  __shared__ float red[128];
  float v = X[(size_t)row * DD + tid] + Y[(size_t)row * DD + tid];
  red[tid] = v; __syncthreads();
  for (int st = 64; st > 0; st >>= 1) { if (tid < st) red[tid] += red[tid + st]; __syncthreads(); }
  float mean = red[0] * (1.0f / DD); __syncthreads();
  float d = v - mean;
  red[tid] = d * d; __syncthreads();
  for (int st = 64; st > 0; st >>= 1) { if (tid < st) red[tid] += red[tid + st]; __syncthreads(); }
  float var = red[0] * (1.0f / DD); __syncthreads();
  Out[(size_t)row * DD + tid] = d * (1.0f / sqrtf(var + 1e-5f)) * g[tid] + b[tid];
}

// ---------------- host-side helpers ----------------
static inline void gemm(const float* A, const float* B, const float* bias,
                        const float* rowscale, const float* scale_ptr, float* C,
                        int M, int N, int K, bool relu, bool acc, hipStream_t s) {
  dim3 g((N + 63) / 64, (M + 63) / 64), b(256);
  if (acc)       gemm_k<false, true ><<<g, b, 0, s>>>(A, B, bias, rowscale, scale_ptr, C, M, N, K);
  else if (relu) gemm_k<true,  false><<<g, b, 0, s>>>(A, B, bias, rowscale, scale_ptr, C, M, N, K);
  else           gemm_k<false, false><<<g, b, 0, s>>>(A, B, bias, rowscale, scale_ptr, C, M, N, K);
}

static void encoder(const float* xin, float* xout,
                    const float* aw, const float* ab,
                    const float* w1, const float* b1,
                    const float* w2, const float* b2,
                    const float* lng, const float* lnb,
                    float* q, float* kb, float* vb, float* ao, float* xl,
                    float* t1, float* f2, hipStream_t s) {
  gemm(xin, aw + 0 * DD * DD, ab + 0 * DD, nullptr, nullptr, q,  SS, DD, DD, false, false, s);
  gemm(xin, aw + 1 * DD * DD, ab + 1 * DD, nullptr, nullptr, kb, SS, DD, DD, false, false, s);
  gemm(xin, aw + 2 * DD * DD, ab + 2 * DD, nullptr, nullptr, vb, SS, DD, DD, false, false, s);
  attn_k<<<dim3(SS, HH), 256, 0, s>>>(q, kb, vb, ao);
  gemm(ao, aw + 3 * DD * DD, ab + 3 * DD, nullptr, nullptr, f2, SS, DD, DD, false, false, s);
  add_ln_k<<<SS, 128, 0, s>>>(xin, f2, lng, lnb, xl);
  gemm(xl, w1, b1, nullptr, nullptr, t1, SS, DFF2, DD, true,  false, s);
  gemm(t1, w2, b2, nullptr, nullptr, f2, SS, DD, DFF2, false, false, s);
  add_ln_k<<<SS, 128, 0, s>>>(xl, f2, lng + DD, lnb + DD, xout);
}

extern "C" void kernel_launch(void* const* d_in, const int* in_sizes, int n_in,
                              void* d_out, int out_size, void* d_ws, size_t ws_size,
                              hipStream_t stream) {
  (void)in_sizes; (void)n_in; (void)out_size; (void)ws_size;
  const float* adj       = (const float*)d_in[0];
  const float* raw_nodes = (const float*)d_in[1];
  const float* proj_w    = (const float*)d_in[2];
  const float* proj_b    = (const float*)d_in[3];
  const float* user_emb  = (const float*)d_in[4];
  const float* item_emb  = (const float*)d_in[5];
  const float* vs        = (const float*)d_in[6];
  const float* alpha_p   = (const float*)d_in[7];
  const float* pgw       = (const float*)d_in[8];
  const float* pgb       = (const float*)d_in[9];
  const float* uaw = (const float*)d_in[10];
  const float* uab = (const float*)d_in[11];
  const float* uw1 = (const float*)d_in[12];
  const float* ub1 = (const float*)d_in[13];
  const float* uw2 = (const float*)d_in[14];
  const float* ub2 = (const float*)d_in[15];
  const float* ulg = (const float*)d_in[16];
  const float* ulb = (const float*)d_in[17];
  const float* iaw = (const float*)d_in[18];
  const float* iab = (const float*)d_in[19];
  const float* iw1 = (const float*)d_in[20];
  const float* ib1 = (const float*)d_in[21];
  const float* iw2 = (const float*)d_in[22];
  const float* ib2 = (const float*)d_in[23];
  const float* ilg = (const float*)d_in[24];
  const float* ilb = (const float*)d_in[25];

  float* w = (float*)d_ws;
  float* pe   = w; w += (size_t)NTOT * DD;
  float* x0   = w; w += (size_t)NTOT * DD;
  float* x1   = w; w += (size_t)NTOT * DD;
  float* x2   = w; w += (size_t)NTOT * DD;
  float* cur  = w; w += (size_t)NTOT * DD;
  float* tmp1 = w; w += (size_t)NTOT * DD;
  float* q    = w; w += (size_t)SS * DD;
  float* kb   = w; w += (size_t)SS * DD;
  float* vb   = w; w += (size_t)SS * DD;
  float* ao   = w; w += (size_t)SS * DD;
  float* xl   = w; w += (size_t)SS * DD;
  float* f2   = w; w += (size_t)SS * DD;
  float* t1   = w; w += (size_t)SS * DFF2;
  float* ps   = w; w += (size_t)II * DD;
  float* dinv = w; w += 4096;
  // topv/topi alias q/kb: consumed by topk_merge_k before encoder touches q/kb.
  float* topv = q;                    // needs NTOT*20 = 122880 floats < SS*DD
  int*   topi = (int*)kb;

  pe_k<<<(NTOT * 64 + 255) / 256, 256, 0, stream>>>(pe);
  dinv_k<<<II, 256, 0, stream>>>(vs, dinv);
  gemm(raw_nodes, proj_w, proj_b, nullptr, nullptr, tmp1, NTOT, DD, 1280, false, false, stream);
  blend_k<<<(NTOT * DD + 255) / 256, 256, 0, stream>>>(tmp1, user_emb, item_emb, alpha_p, x0);

  float* xs[3] = {x0, x1, x2};
  for (int b = 0; b < 2; ++b) {
    const float* prev = xs[b];
    float* outb = xs[b + 1];
    topk_part_k<<<dim3(2, 192), 256, 0, stream>>>(prev, adj, topv, topi);
    topk_merge_k<<<NTOT / 16, 256, 0, stream>>>(topv, topi, adj, prev, cur);
    scale_rows_k<<<(II * DD + 255) / 256, 256, 0, stream>>>(prev + (size_t)UU * DD, dinv, ps);
    gemm(vs, ps, nullptr, dinv, alpha_p, cur + (size_t)UU * DD, II, DD, II, false, true, stream);
    gemm(cur, pgw, pgb, nullptr, nullptr, tmp1, NTOT, DD, DD, false, false, stream);
    gate_pe_k<<<(NTOT * DD + 255) / 256, 256, 0, stream>>>(cur, tmp1, pe);
    encoder(cur,                   outb,                   uaw, uab, uw1, ub1, uw2, ub2, ulg, ulb,
            q, kb, vb, ao, xl, t1, f2, stream);
    encoder(cur + (size_t)UU * DD, outb + (size_t)UU * DD, iaw, iab, iw1, ib1, iw2, ib2, ilg, ilb,
            q, kb, vb, ao, xl, t1, f2, stream);
  }
  final_k<<<(NTOT * DD + 255) / 256, 256, 0, stream>>>(x0, x1, x2, (float*)d_out);
}

// Round 4
// 3141.265 us; speedup vs baseline: 4.5025x; 1.6089x over previous
//
#include <hip/hip_runtime.h>
#include <math.h>

#define NTOT 6144
#define UU   3072
#define II   3072
#define DD   128
#define SS   3072
#define DFF2 512
#define HH   4

// ---------------- sinusoidal PE table ----------------
__global__ void pe_k(float* __restrict__ pe) {
  int idx = blockIdx.x * 256 + threadIdx.x;
  if (idx >= NTOT * 64) return;
  int pos = idx >> 6, j = idx & 63;
  float ex = (2.0f * (float)j) * (-0.07195578415606394f);  // -ln(10000)/128
  float dv = expf(ex);
  float ang = (float)pos * dv;
  pe[(size_t)pos * DD + 2 * j]     = sinf(ang);
  pe[(size_t)pos * DD + 2 * j + 1] = cosf(ang);
}

// ---------------- dinv = (rowsum(vs)+eps)^-0.5 ----------------
__global__ void dinv_k(const float* __restrict__ vs, float* __restrict__ dinv) {
  int i = blockIdx.x, tid = threadIdx.x;
  __shared__ float red[256];
  float s = 0.f;
  const float* row = vs + (size_t)i * II;
  for (int j = tid; j < II; j += 256) s += row[j];
  red[tid] = s; __syncthreads();
  for (int st = 128; st > 0; st >>= 1) { if (tid < st) red[tid] += red[tid + st]; __syncthreads(); }
  if (tid == 0) dinv[i] = 1.0f / sqrtf(red[0] + 1e-7f);
}

// ---------------- shared GEMM core (64x64 tile, f4 LDS reads, prefetch) -------
// Requires M%64==0, N%64==0, K%16==0, 16B-aligned A/B rows.
__device__ __forceinline__ void gemm_core(
    const float* __restrict__ A, const float* __restrict__ B,
    int N, int K, int bm, int bn, int k0beg, int k0end,
    float (*As)[68], float (*Bs)[68], float (&acc)[4][4]) {
  const int tid = threadIdx.x;
  const int am = tid >> 2, ak = (tid & 3) * 4;     // A stage: row am, k-chunk ak
  const int bk = tid >> 4, bnc = (tid & 15) * 4;   // B stage: k-row bk, col-chunk bnc
  const float* Ap = A + (size_t)(bm + am) * K + ak;
  const float* Bp = B + (size_t)bk * N + bn + bnc;
  float4 av = *(const float4*)(Ap + k0beg);
  float4 bv = *(const float4*)(Bp + (size_t)k0beg * N);
  const int tx = tid & 15, ty = tid >> 4;
  for (int k0 = k0beg; k0 < k0end; k0 += 16) {
    __syncthreads();
    As[ak + 0][am] = av.x; As[ak + 1][am] = av.y;
    As[ak + 2][am] = av.z; As[ak + 3][am] = av.w;
    *(float4*)&Bs[bk][bnc] = bv;
    __syncthreads();
    if (k0 + 16 < k0end) {   // prefetch next tile while computing this one
      av = *(const float4*)(Ap + k0 + 16);
      bv = *(const float4*)(Bp + (size_t)(k0 + 16) * N);
    }
#pragma unroll
    for (int kq = 0; kq < 16; ++kq) {
      float4 a4 = *(const float4*)&As[kq][ty * 4];
      float4 b4 = *(const float4*)&Bs[kq][tx * 4];
      const float* ap = (const float*)&a4;
      const float* bp = (const float*)&b4;
#pragma unroll
      for (int i = 0; i < 4; ++i)
#pragma unroll
        for (int j = 0; j < 4; ++j)
          acc[i][j] = fmaf(ap[i], bp[j], acc[i][j]);
    }
  }
}

// C = A@B + bias, optional relu
template<bool RELU>
__global__ __launch_bounds__(256) void gemm_k(
    const float* __restrict__ A, const float* __restrict__ B,
    const float* __restrict__ bias, float* __restrict__ C,
    int M, int N, int K) {
  __shared__ float As[16][68];
  __shared__ float Bs[16][68];
  const int bm = blockIdx.y * 64, bn = blockIdx.x * 64;
  float acc[4][4] = {{0.f}};
  gemm_core(A, B, N, K, bm, bn, 0, K, As, Bs, acc);
  const int tx = threadIdx.x & 15, ty = threadIdx.x >> 4;
#pragma unroll
  for (int i = 0; i < 4; ++i) {
    int row = bm + ty * 4 + i;
    float4 o; float* op = (float*)&o;
#pragma unroll
    for (int j = 0; j < 4; ++j) {
      float v = acc[i][j] + (bias ? bias[bn + tx * 4 + j] : 0.0f);
      if (RELU) v = fmaxf(v, 0.0f);
      op[j] = v;
    }
    *(float4*)&C[(size_t)row * N + bn + tx * 4] = o;
  }
}

// fused QKV: W = [3][D][D], Bias = [>=3][D], Cb = q|k|v contiguous (each SS*DD)
__global__ __launch_bounds__(256) void gemm_qkv_k(
    const float* __restrict__ A, const float* __restrict__ W,
    const float* __restrict__ Bias, float* __restrict__ Cb) {
  __shared__ float As[16][68];
  __shared__ float Bs[16][68];
  const int mat = blockIdx.x >> 1;
  const int bn = (blockIdx.x & 1) * 64;
  const int bm = blockIdx.y * 64;
  const float* B = W + (size_t)mat * DD * DD;
  const float* bias = Bias + mat * DD;
  float* C = Cb + (size_t)mat * SS * DD;
  float acc[4][4] = {{0.f}};
  gemm_core(A, B, DD, DD, bm, bn, 0, DD, As, Bs, acc);
  const int tx = threadIdx.x & 15, ty = threadIdx.x >> 4;
#pragma unroll
  for (int i = 0; i < 4; ++i) {
    int row = bm + ty * 4 + i;
    float4 o; float* op = (float*)&o;
#pragma unroll
    for (int j = 0; j < 4; ++j) op[j] = acc[i][j] + bias[bn + tx * 4 + j];
    *(float4*)&C[(size_t)row * DD + bn + tx * 4] = o;
  }
}

// split-K accumulate: C += rowscale[i]*scale * (A@B chunk); grid.z = K/KCH chunks
__global__ __launch_bounds__(256) void gemm_sk_k(
    const float* __restrict__ A, const float* __restrict__ B,
    const float* __restrict__ rowscale, const float* __restrict__ scale_ptr,
    float* __restrict__ C, int N, int K, int KCH) {
  __shared__ float As[16][68];
  __shared__ float Bs[16][68];
  const int bm = blockIdx.y * 64, bn = blockIdx.x * 64;
  const int kb = blockIdx.z * KCH;
  float acc[4][4] = {{0.f}};
  gemm_core(A, B, N, K, bm, bn, kb, kb + KCH, As, Bs, acc);
  const int tx = threadIdx.x & 15, ty = threadIdx.x >> 4;
  float sc = scale_ptr[0];
#pragma unroll
  for (int i = 0; i < 4; ++i) {
    int row = bm + ty * 4 + i;
    float rs = rowscale[row] * sc;
#pragma unroll
    for (int j = 0; j < 4; ++j)
      atomicAdd(&C[(size_t)row * N + bn + tx * 4 + j], acc[i][j] * rs);
  }
}

// ---------------- top-10 register list insertion (desc, ties -> lower idx) ----
__device__ __forceinline__ void ins10(float (&v)[10], int (&ix)[10], float cv, int ci) {
  if (!((cv > v[9]) || (cv == v[9] && ci < ix[9]))) return;
#pragma unroll
  for (int q = 0; q < 10; ++q) {
    bool b = (cv > v[q]) || (cv == v[q] && ci < ix[q]);
    float ov = v[q]; int oi = ix[q];
    if (b) { v[q] = cv; ix[q] = ci; cv = ov; ci = oi; }
  }
}

// ---------------- top-K partial: per (j-quarter, 32-row tile) -----------------
// scores = 0.5*E_i.E_j + 0.5*adj[i][j] over j in [q*1536, +1536); per-quarter
// sorted top-10 per row -> topv/topi [row][quarter*10+k].
__global__ __launch_bounds__(256) void topk_part_k(
    const float* __restrict__ E, const float* __restrict__ adj,
    float* __restrict__ topv, int* __restrict__ topi) {
  const int quarter = blockIdx.x;      // 0..3
  const int i0 = blockIdx.y * 32;
  const int jb = quarter * 1536;
  const int tid = threadIdx.x;
  const int a0 = tid & 15;             // rows a0, a0+16
  const int b0 = tid >> 4;             // cols b0+16u

  __shared__ __align__(16) unsigned char sm[50688];
  float4* Ei4 = (float4*)sm;                  // 32*33 f4 = 16896 B
  float4* Ej4 = (float4*)(sm + 16896);        // 64*33 f4 = 33792 B
  // post-loop overlays (padded strides: 162 / 17 to avoid bank conflicts)
  float* dv   = (float*)(sm + 0);             // [32][162] (16*10 used)
  int*   di   = (int*)  (sm + 20736);
  float* redv = (float*)(sm + 41472);         // [32][17]
  int*   redi = (int*)  (sm + 43648);
  float* wlv  = (float*)(sm + 45824);         // [32][10]
  int*   wli  = (int*)  (sm + 47104);

  for (int p = 0; p < 4; ++p) {
    int l = tid + p * 256, r = l >> 5, c = l & 31;
    Ei4[r * 33 + c] = ((const float4*)(E + (size_t)(i0 + r) * DD))[c];
  }

  float v0[10], v1[10]; int y0[10], y1[10];
#pragma unroll
  for (int q = 0; q < 10; ++q) { v0[q] = -INFINITY; v1[q] = -INFINITY; y0[q] = 0x7fffffff; y1[q] = 0x7fffffff; }

  // register-prefetch of the first Ej tile
  float4 ejr[8];
#pragma unroll
  for (int p = 0; p < 8; ++p) {
    int l = tid + p * 256, r = l >> 5, c = l & 31;
    ejr[p] = ((const float4*)(E + (size_t)(jb + r) * DD))[c];
  }

  const float* arow0 = adj + (size_t)(i0 + a0) * NTOT;
  const float* arow1 = adj + (size_t)(i0 + a0 + 16) * NTOT;

  for (int jt = 0; jt < 24; ++jt) {
    const int jc = jb + jt * 64;
    __syncthreads();
#pragma unroll
    for (int p = 0; p < 8; ++p) {
      int l = tid + p * 256, r = l >> 5, c = l & 31;
      Ej4[r * 33 + c] = ejr[p];
    }
    __syncthreads();
    if (jt + 1 < 24) {                 // prefetch next Ej tile during compute
      const int jn = jc + 64;
#pragma unroll
      for (int p = 0; p < 8; ++p) {
        int l = tid + p * 256, r = l >> 5, c = l & 31;
        ejr[p] = ((const float4*)(E + (size_t)(jn + r) * DD))[c];
      }
    }
    float ad0[4], ad1[4];
#pragma unroll
    for (int u = 0; u < 4; ++u) {      // issue adj loads early (L1/L2-served)
      int jg = jc + b0 + 16 * u;
      ad0[u] = arow0[jg];
      ad1[u] = arow1[jg];
    }
    float d0[4] = {0.f, 0.f, 0.f, 0.f}, d1[4] = {0.f, 0.f, 0.f, 0.f};
#pragma unroll 8
    for (int kq = 0; kq < 32; ++kq) {
      float4 aa = Ei4[a0 * 33 + kq];
      float4 ab = Ei4[(a0 + 16) * 33 + kq];
#pragma unroll
      for (int u = 0; u < 4; ++u) {
        float4 b = Ej4[(b0 + 16 * u) * 33 + kq];
        d0[u] = fmaf(aa.x, b.x, fmaf(aa.y, b.y, fmaf(aa.z, b.z, fmaf(aa.w, b.w, d0[u]))));
        d1[u] = fmaf(ab.x, b.x, fmaf(ab.y, b.y, fmaf(ab.z, b.z, fmaf(ab.w, b.w, d1[u]))));
      }
    }
#pragma unroll
    for (int u = 0; u < 4; ++u) {
      int jg = jc + b0 + 16 * u;
      ins10(v0, y0, 0.5f * d0[u] + 0.5f * ad0[u], jg);
      ins10(v1, y1, 0.5f * d1[u] + 0.5f * ad1[u], jg);
    }
  }

  __syncthreads();
  const int r0 = a0, r1 = a0 + 16;
#pragma unroll
  for (int q = 0; q < 10; ++q) {
    dv[r0 * 162 + b0 * 10 + q] = v0[q];  di[r0 * 162 + b0 * 10 + q] = y0[q];
    dv[r1 * 162 + b0 * 10 + q] = v1[q];  di[r1 * 162 + b0 * 10 + q] = y1[q];
  }
  __syncthreads();

  int p0 = 0, p1 = 0;
  for (int round = 0; round < 10; ++round) {
    float h0 = dv[r0 * 162 + b0 * 10 + p0]; int h0i = di[r0 * 162 + b0 * 10 + p0];
    float h1 = dv[r1 * 162 + b0 * 10 + p1]; int h1i = di[r1 * 162 + b0 * 10 + p1];
    redv[r0 * 17 + b0] = h0; redi[r0 * 17 + b0] = h0i;
    redv[r1 * 17 + b0] = h1; redi[r1 * 17 + b0] = h1i;
    __syncthreads();
    for (int st = 8; st >= 1; st >>= 1) {
      if (b0 < st) {
        float ov = redv[r0 * 17 + b0 + st]; int oi = redi[r0 * 17 + b0 + st];
        if (ov > redv[r0 * 17 + b0] || (ov == redv[r0 * 17 + b0] && oi < redi[r0 * 17 + b0])) {
          redv[r0 * 17 + b0] = ov; redi[r0 * 17 + b0] = oi;
        }
        ov = redv[r1 * 17 + b0 + st]; oi = redi[r1 * 17 + b0 + st];
        if (ov > redv[r1 * 17 + b0] || (ov == redv[r1 * 17 + b0] && oi < redi[r1 * 17 + b0])) {
          redv[r1 * 17 + b0] = ov; redi[r1 * 17 + b0] = oi;
        }
      }
      __syncthreads();
    }
    int w0 = redi[r0 * 17], w1 = redi[r1 * 17];
    if (b0 == 0) {
      wlv[r0 * 10 + round] = redv[r0 * 17]; wli[r0 * 10 + round] = w0;
      wlv[r1 * 10 + round] = redv[r1 * 17]; wli[r1 * 10 + round] = w1;
    }
    if (w0 == h0i) ++p0;
    if (w1 == h1i) ++p1;
    __syncthreads();
  }

  for (int t = tid; t < 320; t += 256) {
    int row = t / 10, q = t - row * 10;
    int gi = i0 + row;
    topv[(size_t)gi * 40 + quarter * 10 + q] = wlv[row * 10 + q];
    topi[(size_t)gi * 40 + quarter * 10 + q] = wli[row * 10 + q];
  }
}

// ---------------- merge 4 quarter-lists + gather SpMM ----------------
__global__ __launch_bounds__(256) void topk_merge_k(
    const float* __restrict__ topv, const int* __restrict__ topi,
    const float* __restrict__ adj, const float* __restrict__ E,
    float* __restrict__ cur) {
  const int i0 = blockIdx.x * 16, tid = threadIdx.x;
  __shared__ int   midx[16][10];
  __shared__ float madj[16][10];
  if (tid < 16) {
    int row = i0 + tid;
    const float* va = topv + (size_t)row * 40;
    const int*   ia = topi + (size_t)row * 40;
    int pp0 = 0, pp1 = 0, pp2 = 0, pp3 = 0;
    for (int q = 0; q < 10; ++q) {
      float bv = va[pp0]; int bi = ia[pp0]; int bq = 0;
      float cv = va[10 + pp1]; int ci = ia[10 + pp1];
      if (cv > bv || (cv == bv && ci < bi)) { bv = cv; bi = ci; bq = 1; }
      cv = va[20 + pp2]; ci = ia[20 + pp2];
      if (cv > bv || (cv == bv && ci < bi)) { bv = cv; bi = ci; bq = 2; }
      cv = va[30 + pp3]; ci = ia[30 + pp3];
      if (cv > bv || (cv == bv && ci < bi)) { bv = cv; bi = ci; bq = 3; }
      if (bq == 0) ++pp0; else if (bq == 1) ++pp1; else if (bq == 2) ++pp2; else ++pp3;
      midx[tid][q] = bi;
      madj[tid][q] = adj[(size_t)row * NTOT + bi];
    }
  }
  __syncthreads();
  int d = tid & 127, hf = tid >> 7;
  for (int rr = 0; rr < 8; ++rr) {
    int r = rr * 2 + hf;
    float acc = 0.f;
#pragma unroll
    for (int w2 = 0; w2 < 10; ++w2) acc += madj[r][w2] * E[(size_t)midx[r][w2] * DD + d];
    cur[(size_t)(i0 + r) * DD + d] = acc;
  }
}

// ---------------- elementwise helpers ----------------
__global__ void blend_k(const float* __restrict__ rawp, const float* __restrict__ ue,
                        const float* __restrict__ ie, const float* __restrict__ alpha_p,
                        float* __restrict__ x0) {
  int idx = blockIdx.x * 256 + threadIdx.x;
  if (idx >= NTOT * DD) return;
  float a = alpha_p[0];
  float learned = (idx < UU * DD) ? ue[idx] : ie[idx - UU * DD];
  x0[idx] = a * rawp[idx] + (1.0f - a) * learned;
}

__global__ void scale_rows_k(const float* __restrict__ prevI, const float* __restrict__ dinv,
                             float* __restrict__ ps) {
  int idx = blockIdx.x * 256 + threadIdx.x;
  if (idx >= II * DD) return;
  ps[idx] = dinv[idx >> 7] * prevI[idx];
}

__global__ void gate_pe_k(float* __restrict__ cur, const float* __restrict__ tmp,
                          const float* __restrict__ pe) {
  int idx = blockIdx.x * 256 + threadIdx.x;
  if (idx >= NTOT * DD) return;
  float g = 1.0f / (1.0f + expf(-tmp[idx]));
  cur[idx] += g * pe[idx];
}

__global__ void final_k(const float* __restrict__ x0, const float* __restrict__ x1,
                        const float* __restrict__ x2, float* __restrict__ out) {
  int idx = blockIdx.x * 256 + threadIdx.x;
  if (idx >= NTOT * DD) return;
  float v = x0[idx] + 0.75f * x1[idx] + 0.5f * x2[idx];
  out[idx] = v;
  out[NTOT * DD + idx] = v;
}

// ---------------- fused attention (block per (row, head)), K staged via LDS ----
__global__ __launch_bounds__(256) void attn_k(
    const float* __restrict__ Q, const float* __restrict__ Km,
    const float* __restrict__ V, float* __restrict__ O) {
  int s = blockIdx.x, h = blockIdx.y, tid = threadIdx.x;
  int hoff = h * 32;
  __shared__ float scs[SS];
  __shared__ float4 Kt[256 * 9];
  __shared__ float4 qs4[8];
  __shared__ float red[256];
  if (tid < 8) qs4[tid] = ((const float4*)(Q + (size_t)s * DD + hoff))[tid];
  float lmax = -INFINITY;
  for (int t0 = 0; t0 < SS; t0 += 256) {
    __syncthreads();
#pragma unroll
    for (int p = 0; p < 8; ++p) {
      int l = tid + p * 256, r = l >> 3, c = l & 7;
      Kt[r * 9 + c] = ((const float4*)(Km + (size_t)(t0 + r) * DD + hoff))[c];
    }
    __syncthreads();
    float d = 0.f;
#pragma unroll
    for (int t = 0; t < 8; ++t) {
      float4 a = qs4[t], b = Kt[tid * 9 + t];
      d += a.x * b.x + a.y * b.y + a.z * b.z + a.w * b.w;
    }
    d *= 0.17677669529663687f;
    scs[t0 + tid] = d;
    lmax = fmaxf(lmax, d);
  }
  red[tid] = lmax; __syncthreads();
  for (int st = 128; st > 0; st >>= 1) { if (tid < st) red[tid] = fmaxf(red[tid], red[tid + st]); __syncthreads(); }
  float m = red[0]; __syncthreads();
  float lsum = 0.f;
  for (int j = tid; j < SS; j += 256) { float p = expf(scs[j] - m); scs[j] = p; lsum += p; }
  red[tid] = lsum; __syncthreads();
  for (int st = 128; st > 0; st >>= 1) { if (tid < st) red[tid] += red[tid + st]; __syncthreads(); }
  float denom = red[0]; __syncthreads();
  int d = tid & 31, c = tid >> 5;
  float acc = 0.f;
  int j0 = c * (SS / 8), j1 = j0 + (SS / 8);
  for (int j = j0; j < j1; ++j) acc += scs[j] * V[(size_t)j * DD + hoff + d];
  red[tid] = acc; __syncthreads();
  if (tid < 32) {
    float o = 0.f;
#pragma unroll
    for (int cc = 0; cc < 8; ++cc) o += red[cc * 32 + tid];
    O[(size_t)s * DD + hoff + tid] = o / denom;
  }
}

// ---------------- residual + LayerNorm ----------------
__global__ void add_ln_k(const float* __restrict__ X, const float* __restrict__ Y,
                         const float* __restrict__ g, const float* __restrict__ b,
                         float* __restrict__ Out) {
  int row = blockIdx.x, tid = threadIdx.x;
  __shared__ float red[128];
  float v = X[(size_t)row * DD + tid] + Y[(size_t)row * DD + tid];
  red[tid] = v; __syncthreads();
  for (int st = 64; st > 0; st >>= 1) { if (tid < st) red[tid] += red[tid + st]; __syncthreads(); }
  float mean = red[0] * (1.0f / DD); __syncthreads();
  float d = v - mean;
  red[tid] = d * d; __syncthreads();
  for (int st = 64; st > 0; st >>= 1) { if (tid < st) red[tid] += red[tid + st]; __syncthreads(); }
  float var = red[0] * (1.0f / DD); __syncthreads();
  Out[(size_t)row * DD + tid] = d * (1.0f / sqrtf(var + 1e-5f)) * g[tid] + b[tid];
}

// ---------------- host-side encoder ----------------
static void encoder(const float* xin, float* xout,
                    const float* aw, const float* ab,
                    const float* w1, const float* b1,
                    const float* w2, const float* b2,
                    const float* lng, const float* lnb,
                    float* qkv, float* ao, float* xl, float* t1, float* f2,
                    hipStream_t s) {
  gemm_qkv_k<<<dim3(6, SS / 64), 256, 0, s>>>(xin, aw, ab, qkv);
  attn_k<<<dim3(SS, HH), 256, 0, s>>>(qkv, qkv + (size_t)SS * DD, qkv + (size_t)2 * SS * DD, ao);
  gemm_k<false><<<dim3(2, SS / 64), 256, 0, s>>>(ao, aw + 3 * DD * DD, ab + 3 * DD, f2, SS, DD, DD);
  add_ln_k<<<SS, 128, 0, s>>>(xin, f2, lng, lnb, xl);
  gemm_k<true ><<<dim3(8, SS / 64), 256, 0, s>>>(xl, w1, b1, t1, SS, DFF2, DD);
  gemm_k<false><<<dim3(2, SS / 64), 256, 0, s>>>(t1, w2, b2, f2, SS, DD, DFF2);
  add_ln_k<<<SS, 128, 0, s>>>(xl, f2, lng + DD, lnb + DD, xout);
}

extern "C" void kernel_launch(void* const* d_in, const int* in_sizes, int n_in,
                              void* d_out, int out_size, void* d_ws, size_t ws_size,
                              hipStream_t stream) {
  (void)in_sizes; (void)n_in; (void)out_size; (void)ws_size;
  const float* adj       = (const float*)d_in[0];
  const float* raw_nodes = (const float*)d_in[1];
  const float* proj_w    = (const float*)d_in[2];
  const float* proj_b    = (const float*)d_in[3];
  const float* user_emb  = (const float*)d_in[4];
  const float* item_emb  = (const float*)d_in[5];
  const float* vs        = (const float*)d_in[6];
  const float* alpha_p   = (const float*)d_in[7];
  const float* pgw       = (const float*)d_in[8];
  const float* pgb       = (const float*)d_in[9];
  const float* uaw = (const float*)d_in[10];
  const float* uab = (const float*)d_in[11];
  const float* uw1 = (const float*)d_in[12];
  const float* ub1 = (const float*)d_in[13];
  const float* uw2 = (const float*)d_in[14];
  const float* ub2 = (const float*)d_in[15];
  const float* ulg = (const float*)d_in[16];
  const float* ulb = (const float*)d_in[17];
  const float* iaw = (const float*)d_in[18];
  const float* iab = (const float*)d_in[19];
  const float* iw1 = (const float*)d_in[20];
  const float* ib1 = (const float*)d_in[21];
  const float* iw2 = (const float*)d_in[22];
  const float* ib2 = (const float*)d_in[23];
  const float* ilg = (const float*)d_in[24];
  const float* ilb = (const float*)d_in[25];

  float* w = (float*)d_ws;
  float* pe   = w; w += (size_t)NTOT * DD;
  float* x0   = w; w += (size_t)NTOT * DD;
  float* x1   = w; w += (size_t)NTOT * DD;
  float* x2   = w; w += (size_t)NTOT * DD;
  float* cur  = w; w += (size_t)NTOT * DD;
  float* tmp1 = w; w += (size_t)NTOT * DD;
  float* qkv  = w; w += (size_t)3 * SS * DD;
  float* ao   = w; w += (size_t)SS * DD;
  float* xl   = w; w += (size_t)SS * DD;
  float* f2   = w; w += (size_t)SS * DD;
  float* t1   = w; w += (size_t)SS * DFF2;
  float* ps   = w; w += (size_t)II * DD;
  float* dinv = w; w += 4096;
  // topv/topi alias qkv: consumed by topk_merge_k before encoder writes qkv.
  float* topv = qkv;                         // NTOT*40 floats
  int*   topi = (int*)(qkv + (size_t)SS * DD);

  pe_k<<<(NTOT * 64 + 255) / 256, 256, 0, stream>>>(pe);
  dinv_k<<<II, 256, 0, stream>>>(vs, dinv);
  gemm_k<false><<<dim3(2, NTOT / 64), 256, 0, stream>>>(raw_nodes, proj_w, proj_b, tmp1, NTOT, DD, 1280);
  blend_k<<<(NTOT * DD + 255) / 256, 256, 0, stream>>>(tmp1, user_emb, item_emb, alpha_p, x0);

  float* xs[3] = {x0, x1, x2};
  for (int b = 0; b < 2; ++b) {
    const float* prev = xs[b];
    float* outb = xs[b + 1];
    topk_part_k<<<dim3(4, 192), 256, 0, stream>>>(prev, adj, topv, topi);
    topk_merge_k<<<NTOT / 16, 256, 0, stream>>>(topv, topi, adj, prev, cur);
    scale_rows_k<<<(II * DD + 255) / 256, 256, 0, stream>>>(prev + (size_t)UU * DD, dinv, ps);
    // cur[U:] += alpha * dinv_i * (vs @ (dinv_j * prev[U:]))   (split-K x4, atomic)
    gemm_sk_k<<<dim3(2, II / 64, 4), 256, 0, stream>>>(vs, ps, dinv, alpha_p,
                                                       cur + (size_t)UU * DD, DD, II, 768);
    gemm_k<false><<<dim3(2, NTOT / 64), 256, 0, stream>>>(cur, pgw, pgb, tmp1, NTOT, DD, DD);
    gate_pe_k<<<(NTOT * DD + 255) / 256, 256, 0, stream>>>(cur, tmp1, pe);
    encoder(cur,                   outb,                   uaw, uab, uw1, ub1, uw2, ub2, ulg, ulb,
            qkv, ao, xl, t1, f2, stream);
    encoder(cur + (size_t)UU * DD, outb + (size_t)UU * DD, iaw, iab, iw1, ib1, iw2, ib2, ilg, ilb,
            qkv, ao, xl, t1, f2, stream);
  }
  final_k<<<(NTOT * DD + 255) / 256, 256, 0, stream>>>(x0, x1, x2, (float*)d_out);
}

// Round 5
// 2363.476 us; speedup vs baseline: 5.9843x; 1.3291x over previous
//
#include <hip/hip_runtime.h>
#include <math.h>

#define NTOT 6144
#define UU   3072
#define II   3072
#define DD   128
#define SS   3072
#define DFF2 512
#define HH   4

// ---------------- sinusoidal PE table ----------------
__global__ void pe_k(float* __restrict__ pe) {
  int idx = blockIdx.x * 256 + threadIdx.x;
  if (idx >= NTOT * 64) return;
  int pos = idx >> 6, j = idx & 63;
  float ex = (2.0f * (float)j) * (-0.07195578415606394f);  // -ln(10000)/128
  float dv = expf(ex);
  float ang = (float)pos * dv;
  pe[(size_t)pos * DD + 2 * j]     = sinf(ang);
  pe[(size_t)pos * DD + 2 * j + 1] = cosf(ang);
}

// ---------------- dinv = (rowsum(vs)+eps)^-0.5 ----------------
__global__ void dinv_k(const float* __restrict__ vs, float* __restrict__ dinv) {
  int i = blockIdx.x, tid = threadIdx.x;
  __shared__ float red[256];
  float s = 0.f;
  const float* row = vs + (size_t)i * II;
  for (int j = tid; j < II; j += 256) s += row[j];
  red[tid] = s; __syncthreads();
  for (int st = 128; st > 0; st >>= 1) { if (tid < st) red[tid] += red[tid + st]; __syncthreads(); }
  if (tid == 0) dinv[i] = 1.0f / sqrtf(red[0] + 1e-7f);
}

// ---------------- shared GEMM core (64x64 tile, f4 LDS reads, prefetch) -------
__device__ __forceinline__ void gemm_core(
    const float* __restrict__ A, const float* __restrict__ B,
    int N, int K, int bm, int bn, int k0beg, int k0end,
    float (*As)[68], float (*Bs)[68], float (&acc)[4][4]) {
  const int tid = threadIdx.x;
  const int am = tid >> 2, ak = (tid & 3) * 4;
  const int bk = tid >> 4, bnc = (tid & 15) * 4;
  const float* Ap = A + (size_t)(bm + am) * K + ak;
  const float* Bp = B + (size_t)bk * N + bn + bnc;
  float4 av = *(const float4*)(Ap + k0beg);
  float4 bv = *(const float4*)(Bp + (size_t)k0beg * N);
  const int tx = tid & 15, ty = tid >> 4;
  for (int k0 = k0beg; k0 < k0end; k0 += 16) {
    __syncthreads();
    As[ak + 0][am] = av.x; As[ak + 1][am] = av.y;
    As[ak + 2][am] = av.z; As[ak + 3][am] = av.w;
    *(float4*)&Bs[bk][bnc] = bv;
    __syncthreads();
    if (k0 + 16 < k0end) {
      av = *(const float4*)(Ap + k0 + 16);
      bv = *(const float4*)(Bp + (size_t)(k0 + 16) * N);
    }
#pragma unroll
    for (int kq = 0; kq < 16; ++kq) {
      float4 a4 = *(const float4*)&As[kq][ty * 4];
      float4 b4 = *(const float4*)&Bs[kq][tx * 4];
      const float* ap = (const float*)&a4;
      const float* bp = (const float*)&b4;
#pragma unroll
      for (int i = 0; i < 4; ++i)
#pragma unroll
        for (int j = 0; j < 4; ++j)
          acc[i][j] = fmaf(ap[i], bp[j], acc[i][j]);
    }
  }
}

template<bool RELU>
__global__ __launch_bounds__(256, 4) void gemm_k(
    const float* __restrict__ A, const float* __restrict__ B,
    const float* __restrict__ bias, float* __restrict__ C,
    int M, int N, int K) {
  __shared__ float As[16][68];
  __shared__ float Bs[16][68];
  const int bm = blockIdx.y * 64, bn = blockIdx.x * 64;
  float acc[4][4] = {{0.f}};
  gemm_core(A, B, N, K, bm, bn, 0, K, As, Bs, acc);
  const int tx = threadIdx.x & 15, ty = threadIdx.x >> 4;
#pragma unroll
  for (int i = 0; i < 4; ++i) {
    int row = bm + ty * 4 + i;
    float4 o; float* op = (float*)&o;
#pragma unroll
    for (int j = 0; j < 4; ++j) {
      float v = acc[i][j] + (bias ? bias[bn + tx * 4 + j] : 0.0f);
      if (RELU) v = fmaxf(v, 0.0f);
      op[j] = v;
    }
    *(float4*)&C[(size_t)row * N + bn + tx * 4] = o;
  }
}

__global__ __launch_bounds__(256, 4) void gemm_qkv_k(
    const float* __restrict__ A, const float* __restrict__ W,
    const float* __restrict__ Bias, float* __restrict__ Cb) {
  __shared__ float As[16][68];
  __shared__ float Bs[16][68];
  const int mat = blockIdx.x >> 1;
  const int bn = (blockIdx.x & 1) * 64;
  const int bm = blockIdx.y * 64;
  const float* B = W + (size_t)mat * DD * DD;
  const float* bias = Bias + mat * DD;
  float* C = Cb + (size_t)mat * SS * DD;
  float acc[4][4] = {{0.f}};
  gemm_core(A, B, DD, DD, bm, bn, 0, DD, As, Bs, acc);
  const int tx = threadIdx.x & 15, ty = threadIdx.x >> 4;
#pragma unroll
  for (int i = 0; i < 4; ++i) {
    int row = bm + ty * 4 + i;
    float4 o; float* op = (float*)&o;
#pragma unroll
    for (int j = 0; j < 4; ++j) op[j] = acc[i][j] + bias[bn + tx * 4 + j];
    *(float4*)&C[(size_t)row * DD + bn + tx * 4] = o;
  }
}

__global__ __launch_bounds__(256, 4) void gemm_sk_k(
    const float* __restrict__ A, const float* __restrict__ B,
    const float* __restrict__ rowscale, const float* __restrict__ scale_ptr,
    float* __restrict__ C, int N, int K, int KCH) {
  __shared__ float As[16][68];
  __shared__ float Bs[16][68];
  const int bm = blockIdx.y * 64, bn = blockIdx.x * 64;
  const int kb = blockIdx.z * KCH;
  float acc[4][4] = {{0.f}};
  gemm_core(A, B, N, K, bm, bn, kb, kb + KCH, As, Bs, acc);
  const int tx = threadIdx.x & 15, ty = threadIdx.x >> 4;
  float sc = scale_ptr[0];
#pragma unroll
  for (int i = 0; i < 4; ++i) {
    int row = bm + ty * 4 + i;
    float rs = rowscale[row] * sc;
#pragma unroll
    for (int j = 0; j < 4; ++j)
      atomicAdd(&C[(size_t)row * N + bn + tx * 4 + j], acc[i][j] * rs);
  }
}

// ---------------- top-10 register list insertion (desc, ties -> lower idx) ----
__device__ __forceinline__ void ins10(float (&v)[10], int (&ix)[10], float cv, int ci) {
  if (!((cv > v[9]) || (cv == v[9] && ci < ix[9]))) return;
#pragma unroll
  for (int q = 0; q < 10; ++q) {
    bool b = (cv > v[q]) || (cv == v[q] && ci < ix[q]);
    float ov = v[q]; int oi = ix[q];
    if (b) { v[q] = cv; ix[q] = ci; cv = ov; ci = oi; }
  }
}

// ---------------- top-K partial: per (j-quarter, 32-row tile) -----------------
// launch_bounds (256,3): VGPR cap 170 — round-4 build chose 68 VGPRs and
// spilled the top-10 lists to scratch (545 MB HBM writes/dispatch).
__global__ __launch_bounds__(256, 3) void topk_part_k(
    const float* __restrict__ E, const float* __restrict__ adj,
    float* __restrict__ topv, int* __restrict__ topi) {
  const int quarter = blockIdx.x;      // 0..3
  const int i0 = blockIdx.y * 32;
  const int jb = quarter * 1536;
  const int tid = threadIdx.x;
  const int a0 = tid & 15;
  const int b0 = tid >> 4;

  __shared__ __align__(16) unsigned char sm[50688];
  float4* Ei4 = (float4*)sm;                  // 32*33 f4 = 16896 B
  float4* Ej4 = (float4*)(sm + 16896);        // 64*33 f4 = 33792 B
  float* dv   = (float*)(sm + 0);             // [32][162]
  int*   di   = (int*)  (sm + 20736);
  float* redv = (float*)(sm + 41472);         // [32][17]
  int*   redi = (int*)  (sm + 43648);
  float* wlv  = (float*)(sm + 45824);         // [32][10]
  int*   wli  = (int*)  (sm + 47104);

  for (int p = 0; p < 4; ++p) {
    int l = tid + p * 256, r = l >> 5, c = l & 31;
    Ei4[r * 33 + c] = ((const float4*)(E + (size_t)(i0 + r) * DD))[c];
  }

  float v0[10], v1[10]; int y0[10], y1[10];
#pragma unroll
  for (int q = 0; q < 10; ++q) { v0[q] = -INFINITY; v1[q] = -INFINITY; y0[q] = 0x7fffffff; y1[q] = 0x7fffffff; }

  float4 ejr[8];
#pragma unroll
  for (int p = 0; p < 8; ++p) {
    int l = tid + p * 256, r = l >> 5, c = l & 31;
    ejr[p] = ((const float4*)(E + (size_t)(jb + r) * DD))[c];
  }

  const float* arow0 = adj + (size_t)(i0 + a0) * NTOT;
  const float* arow1 = adj + (size_t)(i0 + a0 + 16) * NTOT;

  for (int jt = 0; jt < 24; ++jt) {
    const int jc = jb + jt * 64;
    __syncthreads();
#pragma unroll
    for (int p = 0; p < 8; ++p) {
      int l = tid + p * 256, r = l >> 5, c = l & 31;
      Ej4[r * 33 + c] = ejr[p];
    }
    __syncthreads();
    if (jt + 1 < 24) {
      const int jn = jc + 64;
#pragma unroll
      for (int p = 0; p < 8; ++p) {
        int l = tid + p * 256, r = l >> 5, c = l & 31;
        ejr[p] = ((const float4*)(E + (size_t)(jn + r) * DD))[c];
      }
    }
    float ad0[4], ad1[4];
#pragma unroll
    for (int u = 0; u < 4; ++u) {
      int jg = jc + b0 + 16 * u;
      ad0[u] = arow0[jg];
      ad1[u] = arow1[jg];
    }
    float d0[4] = {0.f, 0.f, 0.f, 0.f}, d1[4] = {0.f, 0.f, 0.f, 0.f};
#pragma unroll 8
    for (int kq = 0; kq < 32; ++kq) {
      float4 aa = Ei4[a0 * 33 + kq];
      float4 ab = Ei4[(a0 + 16) * 33 + kq];
#pragma unroll
      for (int u = 0; u < 4; ++u) {
        float4 b = Ej4[(b0 + 16 * u) * 33 + kq];
        d0[u] = fmaf(aa.x, b.x, fmaf(aa.y, b.y, fmaf(aa.z, b.z, fmaf(aa.w, b.w, d0[u]))));
        d1[u] = fmaf(ab.x, b.x, fmaf(ab.y, b.y, fmaf(ab.z, b.z, fmaf(ab.w, b.w, d1[u]))));
      }
    }
#pragma unroll
    for (int u = 0; u < 4; ++u) {
      int jg = jc + b0 + 16 * u;
      ins10(v0, y0, 0.5f * d0[u] + 0.5f * ad0[u], jg);
      ins10(v1, y1, 0.5f * d1[u] + 0.5f * ad1[u], jg);
    }
  }

  __syncthreads();
  const int r0 = a0, r1 = a0 + 16;
#pragma unroll
  for (int q = 0; q < 10; ++q) {
    dv[r0 * 162 + b0 * 10 + q] = v0[q];  di[r0 * 162 + b0 * 10 + q] = y0[q];
    dv[r1 * 162 + b0 * 10 + q] = v1[q];  di[r1 * 162 + b0 * 10 + q] = y1[q];
  }
  __syncthreads();

  int p0 = 0, p1 = 0;
  for (int round = 0; round < 10; ++round) {
    float h0 = dv[r0 * 162 + b0 * 10 + p0]; int h0i = di[r0 * 162 + b0 * 10 + p0];
    float h1 = dv[r1 * 162 + b0 * 10 + p1]; int h1i = di[r1 * 162 + b0 * 10 + p1];
    redv[r0 * 17 + b0] = h0; redi[r0 * 17 + b0] = h0i;
    redv[r1 * 17 + b0] = h1; redi[r1 * 17 + b0] = h1i;
    __syncthreads();
    for (int st = 8; st >= 1; st >>= 1) {
      if (b0 < st) {
        float ov = redv[r0 * 17 + b0 + st]; int oi = redi[r0 * 17 + b0 + st];
        if (ov > redv[r0 * 17 + b0] || (ov == redv[r0 * 17 + b0] && oi < redi[r0 * 17 + b0])) {
          redv[r0 * 17 + b0] = ov; redi[r0 * 17 + b0] = oi;
        }
        ov = redv[r1 * 17 + b0 + st]; oi = redi[r1 * 17 + b0 + st];
        if (ov > redv[r1 * 17 + b0] || (ov == redv[r1 * 17 + b0] && oi < redi[r1 * 17 + b0])) {
          redv[r1 * 17 + b0] = ov; redi[r1 * 17 + b0] = oi;
        }
      }
      __syncthreads();
    }
    int w0 = redi[r0 * 17], w1 = redi[r1 * 17];
    if (b0 == 0) {
      wlv[r0 * 10 + round] = redv[r0 * 17]; wli[r0 * 10 + round] = w0;
      wlv[r1 * 10 + round] = redv[r1 * 17]; wli[r1 * 10 + round] = w1;
    }
    if (w0 == h0i) ++p0;
    if (w1 == h1i) ++p1;
    __syncthreads();
  }

  for (int t = tid; t < 320; t += 256) {
    int row = t / 10, q = t - row * 10;
    int gi = i0 + row;
    topv[(size_t)gi * 40 + quarter * 10 + q] = wlv[row * 10 + q];
    topi[(size_t)gi * 40 + quarter * 10 + q] = wli[row * 10 + q];
  }
}

// ---------------- merge 4 quarter-lists + gather SpMM ----------------
__global__ __launch_bounds__(256) void topk_merge_k(
    const float* __restrict__ topv, const int* __restrict__ topi,
    const float* __restrict__ adj, const float* __restrict__ E,
    float* __restrict__ cur) {
  const int i0 = blockIdx.x * 16, tid = threadIdx.x;
  __shared__ int   midx[16][10];
  __shared__ float madj[16][10];
  if (tid < 16) {
    int row = i0 + tid;
    const float* va = topv + (size_t)row * 40;
    const int*   ia = topi + (size_t)row * 40;
    int pp0 = 0, pp1 = 0, pp2 = 0, pp3 = 0;
    for (int q = 0; q < 10; ++q) {
      float bv = va[pp0]; int bi = ia[pp0]; int bq = 0;
      float cv = va[10 + pp1]; int ci = ia[10 + pp1];
      if (cv > bv || (cv == bv && ci < bi)) { bv = cv; bi = ci; bq = 1; }
      cv = va[20 + pp2]; ci = ia[20 + pp2];
      if (cv > bv || (cv == bv && ci < bi)) { bv = cv; bi = ci; bq = 2; }
      cv = va[30 + pp3]; ci = ia[30 + pp3];
      if (cv > bv || (cv == bv && ci < bi)) { bv = cv; bi = ci; bq = 3; }
      if (bq == 0) ++pp0; else if (bq == 1) ++pp1; else if (bq == 2) ++pp2; else ++pp3;
      midx[tid][q] = bi;
      madj[tid][q] = adj[(size_t)row * NTOT + bi];
    }
  }
  __syncthreads();
  int d = tid & 127, hf = tid >> 7;
  for (int rr = 0; rr < 8; ++rr) {
    int r = rr * 2 + hf;
    float acc = 0.f;
#pragma unroll
    for (int w2 = 0; w2 < 10; ++w2) acc += madj[r][w2] * E[(size_t)midx[r][w2] * DD + d];
    cur[(size_t)(i0 + r) * DD + d] = acc;
  }
}

// ---------------- elementwise helpers ----------------
__global__ void blend_k(const float* __restrict__ rawp, const float* __restrict__ ue,
                        const float* __restrict__ ie, const float* __restrict__ alpha_p,
                        float* __restrict__ x0) {
  int idx = blockIdx.x * 256 + threadIdx.x;
  if (idx >= NTOT * DD) return;
  float a = alpha_p[0];
  float learned = (idx < UU * DD) ? ue[idx] : ie[idx - UU * DD];
  x0[idx] = a * rawp[idx] + (1.0f - a) * learned;
}

__global__ void scale_rows_k(const float* __restrict__ prevI, const float* __restrict__ dinv,
                             float* __restrict__ ps) {
  int idx = blockIdx.x * 256 + threadIdx.x;
  if (idx >= II * DD) return;
  ps[idx] = dinv[idx >> 7] * prevI[idx];
}

__global__ void gate_pe_k(float* __restrict__ cur, const float* __restrict__ tmp,
                          const float* __restrict__ pe) {
  int idx = blockIdx.x * 256 + threadIdx.x;
  if (idx >= NTOT * DD) return;
  float g = 1.0f / (1.0f + expf(-tmp[idx]));
  cur[idx] += g * pe[idx];
}

__global__ void final_k(const float* __restrict__ x0, const float* __restrict__ x1,
                        const float* __restrict__ x2, float* __restrict__ out) {
  int idx = blockIdx.x * 256 + threadIdx.x;
  if (idx >= NTOT * DD) return;
  float v = x0[idx] + 0.75f * x1[idx] + 0.5f * x2[idx];
  out[idx] = v;
  out[NTOT * DD + idx] = v;
}

// ---------------- flash attention: 16 q-rows x 64-key tiles per block --------
// thread (r = tid>>4, g = tid&15); a row's 16 g-threads are contiguous lanes
// within one wave -> shfl_xor row reductions, no LDS/barriers for max/sum.
__global__ __launch_bounds__(256, 3) void attn_k(
    const float* __restrict__ Q, const float* __restrict__ Km,
    const float* __restrict__ V, float* __restrict__ O) {
  const int qb = blockIdx.x * 16;
  const int hoff = blockIdx.y * 32;
  const int tid = threadIdx.x;
  const int r = tid >> 4, g = tid & 15;
  const int jh = g >> 3, d4 = g & 7;
  __shared__ float4 Kt[64 * 9];
  __shared__ float4 Vt[64 * 9];
  __shared__ float  P[16 * 68];

  float4 qr[8];
  const float4* Qp = (const float4*)(Q + (size_t)(qb + r) * DD + hoff);
#pragma unroll
  for (int t = 0; t < 8; ++t) {
    float4 v = Qp[t];
    v.x *= 0.17677669529663687f; v.y *= 0.17677669529663687f;  // 1/sqrt(32)
    v.z *= 0.17677669529663687f; v.w *= 0.17677669529663687f;
    qr[t] = v;
  }
  float m_run = -INFINITY, l_run = 0.f;
  float4 acc = {0.f, 0.f, 0.f, 0.f};   // dims 4*d4..+3, keys of jh-half

  for (int t0 = 0; t0 < SS; t0 += 64) {
    __syncthreads();                   // prev-iter LDS use done before restage
#pragma unroll
    for (int p = 0; p < 2; ++p) {
      int l = tid + p * 256, row = l >> 3, c = l & 7;
      Kt[row * 9 + c] = ((const float4*)(Km + (size_t)(t0 + row) * DD + hoff))[c];
      Vt[row * 9 + c] = ((const float4*)(V  + (size_t)(t0 + row) * DD + hoff))[c];
    }
    __syncthreads();
    // scores for j = g + 16q (stride-16 mapping: conflict-free Kt reads)
    float s[4];
#pragma unroll
    for (int q = 0; q < 4; ++q) {
      const float4* Kr = &Kt[(g + 16 * q) * 9];
      float d = 0.f;
#pragma unroll
      for (int t = 0; t < 8; ++t) {
        float4 a = qr[t], b = Kr[t];
        d = fmaf(a.x, b.x, fmaf(a.y, b.y, fmaf(a.z, b.z, fmaf(a.w, b.w, d))));
      }
      s[q] = d;
    }
    float tm = fmaxf(fmaxf(s[0], s[1]), fmaxf(s[2], s[3]));
#pragma unroll
    for (int off = 1; off < 16; off <<= 1) tm = fmaxf(tm, __shfl_xor(tm, off, 64));
    float m_new = fmaxf(m_run, tm);
    float sc = expf(m_run - m_new);    // first tile: exp(-inf)=0, acc=0 anyway
    float ts = 0.f;
#pragma unroll
    for (int q = 0; q < 4; ++q) {
      float p = expf(s[q] - m_new);
      ts += p;
      P[r * 68 + g + 16 * q] = p;
    }
#pragma unroll
    for (int off = 1; off < 16; off <<= 1) ts += __shfl_xor(ts, off, 64);
    l_run = l_run * sc + ts;
    m_run = m_new;
    acc.x *= sc; acc.y *= sc; acc.z *= sc; acc.w *= sc;
    __syncthreads();                   // P visible before PV reads
    const float* Prow = &P[r * 68 + jh * 32];
#pragma unroll
    for (int jj4 = 0; jj4 < 8; ++jj4) {
      float4 pv = *(const float4*)(Prow + jj4 * 4);
      const float* pp = (const float*)&pv;
#pragma unroll
      for (int c = 0; c < 4; ++c) {
        float4 v4 = Vt[(jh * 32 + jj4 * 4 + c) * 9 + d4];
        acc.x = fmaf(pp[c], v4.x, acc.x);
        acc.y = fmaf(pp[c], v4.y, acc.y);
        acc.z = fmaf(pp[c], v4.z, acc.z);
        acc.w = fmaf(pp[c], v4.w, acc.w);
      }
    }
  }
  // combine the two jh key-halves (lanes differ in bit 3)
  acc.x += __shfl_xor(acc.x, 8, 64);
  acc.y += __shfl_xor(acc.y, 8, 64);
  acc.z += __shfl_xor(acc.z, 8, 64);
  acc.w += __shfl_xor(acc.w, 8, 64);
  if (jh == 0) {
    float inv = 1.0f / l_run;
    float4 o = {acc.x * inv, acc.y * inv, acc.z * inv, acc.w * inv};
    *(float4*)(O + (size_t)(qb + r) * DD + hoff + d4 * 4) = o;
  }
}

// ---------------- residual + LayerNorm ----------------
__global__ void add_ln_k(const float* __restrict__ X, const float* __restrict__ Y,
                         const float* __restrict__ g, const float* __restrict__ b,
                         float* __restrict__ Out) {
  int row = blockIdx.x, tid = threadIdx.x;
  __shared__ float red[128];
  float v = X[(size_t)row * DD + tid] + Y[(size_t)row * DD + tid];
  red[tid] = v; __syncthreads();
  for (int st = 64; st > 0; st >>= 1) { if (tid < st) red[tid] += red[tid + st]; __syncthreads(); }
  float mean = red[0] * (1.0f / DD); __syncthreads();
  float d = v - mean;
  red[tid] = d * d; __syncthreads();
  for (int st = 64; st > 0; st >>= 1) { if (tid < st) red[tid] += red[tid + st]; __syncthreads(); }
  float var = red[0] * (1.0f / DD); __syncthreads();
  Out[(size_t)row * DD + tid] = d * (1.0f / sqrtf(var + 1e-5f)) * g[tid] + b[tid];
}

// ---------------- host-side encoder ----------------
static void encoder(const float* xin, float* xout,
                    const float* aw, const float* ab,
                    const float* w1, const float* b1,
                    const float* w2, const float* b2,
                    const float* lng, const float* lnb,
                    float* qkv, float* ao, float* xl, float* t1, float* f2,
                    hipStream_t s) {
  gemm_qkv_k<<<dim3(6, SS / 64), 256, 0, s>>>(xin, aw, ab, qkv);
  attn_k<<<dim3(SS / 16, HH), 256, 0, s>>>(qkv, qkv + (size_t)SS * DD, qkv + (size_t)2 * SS * DD, ao);
  gemm_k<false><<<dim3(2, SS / 64), 256, 0, s>>>(ao, aw + 3 * DD * DD, ab + 3 * DD, f2, SS, DD, DD);
  add_ln_k<<<SS, 128, 0, s>>>(xin, f2, lng, lnb, xl);
  gemm_k<true ><<<dim3(8, SS / 64), 256, 0, s>>>(xl, w1, b1, t1, SS, DFF2, DD);
  gemm_k<false><<<dim3(2, SS / 64), 256, 0, s>>>(t1, w2, b2, f2, SS, DD, DFF2);
  add_ln_k<<<SS, 128, 0, s>>>(xl, f2, lng + DD, lnb + DD, xout);
}

extern "C" void kernel_launch(void* const* d_in, const int* in_sizes, int n_in,
                              void* d_out, int out_size, void* d_ws, size_t ws_size,
                              hipStream_t stream) {
  (void)in_sizes; (void)n_in; (void)out_size; (void)ws_size;
  const float* adj       = (const float*)d_in[0];
  const float* raw_nodes = (const float*)d_in[1];
  const float* proj_w    = (const float*)d_in[2];
  const float* proj_b    = (const float*)d_in[3];
  const float* user_emb  = (const float*)d_in[4];
  const float* item_emb  = (const float*)d_in[5];
  const float* vs        = (const float*)d_in[6];
  const float* alpha_p   = (const float*)d_in[7];
  const float* pgw       = (const float*)d_in[8];
  const float* pgb       = (const float*)d_in[9];
  const float* uaw = (const float*)d_in[10];
  const float* uab = (const float*)d_in[11];
  const float* uw1 = (const float*)d_in[12];
  const float* ub1 = (const float*)d_in[13];
  const float* uw2 = (const float*)d_in[14];
  const float* ub2 = (const float*)d_in[15];
  const float* ulg = (const float*)d_in[16];
  const float* ulb = (const float*)d_in[17];
  const float* iaw = (const float*)d_in[18];
  const float* iab = (const float*)d_in[19];
  const float* iw1 = (const float*)d_in[20];
  const float* ib1 = (const float*)d_in[21];
  const float* iw2 = (const float*)d_in[22];
  const float* ib2 = (const float*)d_in[23];
  const float* ilg = (const float*)d_in[24];
  const float* ilb = (const float*)d_in[25];

  float* w = (float*)d_ws;
  float* pe   = w; w += (size_t)NTOT * DD;
  float* x0   = w; w += (size_t)NTOT * DD;
  float* x1   = w; w += (size_t)NTOT * DD;
  float* x2   = w; w += (size_t)NTOT * DD;
  float* cur  = w; w += (size_t)NTOT * DD;
  float* tmp1 = w; w += (size_t)NTOT * DD;
  float* qkv  = w; w += (size_t)3 * SS * DD;
  float* ao   = w; w += (size_t)SS * DD;
  float* xl   = w; w += (size_t)SS * DD;
  float* f2   = w; w += (size_t)SS * DD;
  float* t1   = w; w += (size_t)SS * DFF2;
  float* ps   = w; w += (size_t)II * DD;
  float* dinv = w; w += 4096;
  float* topv = qkv;                         // alias: dead before encoder runs
  int*   topi = (int*)(qkv + (size_t)SS * DD);

  pe_k<<<(NTOT * 64 + 255) / 256, 256, 0, stream>>>(pe);
  dinv_k<<<II, 256, 0, stream>>>(vs, dinv);
  gemm_k<false><<<dim3(2, NTOT / 64), 256, 0, stream>>>(raw_nodes, proj_w, proj_b, tmp1, NTOT, DD, 1280);
  blend_k<<<(NTOT * DD + 255) / 256, 256, 0, stream>>>(tmp1, user_emb, item_emb, alpha_p, x0);

  float* xs[3] = {x0, x1, x2};
  for (int b = 0; b < 2; ++b) {
    const float* prev = xs[b];
    float* outb = xs[b + 1];
    topk_part_k<<<dim3(4, 192), 256, 0, stream>>>(prev, adj, topv, topi);
    topk_merge_k<<<NTOT / 16, 256, 0, stream>>>(topv, topi, adj, prev, cur);
    scale_rows_k<<<(II * DD + 255) / 256, 256, 0, stream>>>(prev + (size_t)UU * DD, dinv, ps);
    gemm_sk_k<<<dim3(2, II / 64, 4), 256, 0, stream>>>(vs, ps, dinv, alpha_p,
                                                       cur + (size_t)UU * DD, DD, II, 768);
    gemm_k<false><<<dim3(2, NTOT / 64), 256, 0, stream>>>(cur, pgw, pgb, tmp1, NTOT, DD, DD);
    gate_pe_k<<<(NTOT * DD + 255) / 256, 256, 0, stream>>>(cur, tmp1, pe);
    encoder(cur,                   outb,                   uaw, uab, uw1, ub1, uw2, ub2, ulg, ulb,
            qkv, ao, xl, t1, f2, stream);
    encoder(cur + (size_t)UU * DD, outb + (size_t)UU * DD, iaw, iab, iw1, ib1, iw2, ib2, ilg, ilb,
            qkv, ao, xl, t1, f2, stream);
  }
  final_k<<<(NTOT * DD + 255) / 256, 256, 0, stream>>>(x0, x1, x2, (float*)d_out);
}

// Round 6
// 1962.667 us; speedup vs baseline: 7.2064x; 1.2042x over previous
//
#include <hip/hip_runtime.h>
#include <math.h>

#define NTOT 6144
#define UU   3072
#define II   3072
#define DD   128
#define SS   3072
#define DFF2 512
#define HH   4

// ---------------- sinusoidal PE table ----------------
__global__ void pe_k(float* __restrict__ pe) {
  int idx = blockIdx.x * 256 + threadIdx.x;
  if (idx >= NTOT * 64) return;
  int pos = idx >> 6, j = idx & 63;
  float ex = (2.0f * (float)j) * (-0.07195578415606394f);  // -ln(10000)/128
  float dv = expf(ex);
  float ang = (float)pos * dv;
  pe[(size_t)pos * DD + 2 * j]     = sinf(ang);
  pe[(size_t)pos * DD + 2 * j + 1] = cosf(ang);
}

// ---------------- dinv = (rowsum(vs)+eps)^-0.5 ----------------
__global__ void dinv_k(const float* __restrict__ vs, float* __restrict__ dinv) {
  int i = blockIdx.x, tid = threadIdx.x;
  __shared__ float red[256];
  float s = 0.f;
  const float* row = vs + (size_t)i * II;
  for (int j = tid; j < II; j += 256) s += row[j];
  red[tid] = s; __syncthreads();
  for (int st = 128; st > 0; st >>= 1) { if (tid < st) red[tid] += red[tid + st]; __syncthreads(); }
  if (tid == 0) dinv[i] = 1.0f / sqrtf(red[0] + 1e-7f);
}

// ---------------- shared GEMM core (64x64 tile, f4 LDS reads, prefetch) -------
__device__ __forceinline__ void gemm_core(
    const float* __restrict__ A, const float* __restrict__ B,
    int N, int K, int bm, int bn, int k0beg, int k0end,
    float (*As)[68], float (*Bs)[68], float (&acc)[4][4]) {
  const int tid = threadIdx.x;
  const int am = tid >> 2, ak = (tid & 3) * 4;
  const int bk = tid >> 4, bnc = (tid & 15) * 4;
  const float* Ap = A + (size_t)(bm + am) * K + ak;
  const float* Bp = B + (size_t)bk * N + bn + bnc;
  float4 av = *(const float4*)(Ap + k0beg);
  float4 bv = *(const float4*)(Bp + (size_t)k0beg * N);
  const int tx = tid & 15, ty = tid >> 4;
  for (int k0 = k0beg; k0 < k0end; k0 += 16) {
    __syncthreads();
    As[ak + 0][am] = av.x; As[ak + 1][am] = av.y;
    As[ak + 2][am] = av.z; As[ak + 3][am] = av.w;
    *(float4*)&Bs[bk][bnc] = bv;
    __syncthreads();
    if (k0 + 16 < k0end) {
      av = *(const float4*)(Ap + k0 + 16);
      bv = *(const float4*)(Bp + (size_t)(k0 + 16) * N);
    }
#pragma unroll
    for (int kq = 0; kq < 16; ++kq) {
      float4 a4 = *(const float4*)&As[kq][ty * 4];
      float4 b4 = *(const float4*)&Bs[kq][tx * 4];
      const float* ap = (const float*)&a4;
      const float* bp = (const float*)&b4;
#pragma unroll
      for (int i = 0; i < 4; ++i)
#pragma unroll
        for (int j = 0; j < 4; ++j)
          acc[i][j] = fmaf(ap[i], bp[j], acc[i][j]);
    }
  }
}

// plain: C = A@B + bias (optional relu)
template<bool RELU>
__global__ __launch_bounds__(256, 4) void gemm_k(
    const float* __restrict__ A, const float* __restrict__ B,
    const float* __restrict__ bias, float* __restrict__ C,
    int M, int N, int K) {
  __shared__ float As[16][68];
  __shared__ float Bs[16][68];
  const int bm = blockIdx.y * 64, bn = blockIdx.x * 64;
  float acc[4][4] = {{0.f}};
  gemm_core(A, B, N, K, bm, bn, 0, K, As, Bs, acc);
  const int tx = threadIdx.x & 15, ty = threadIdx.x >> 4;
#pragma unroll
  for (int i = 0; i < 4; ++i) {
    int row = bm + ty * 4 + i;
    float4 o; float* op = (float*)&o;
#pragma unroll
    for (int j = 0; j < 4; ++j) {
      float v = acc[i][j] + (bias ? bias[bn + tx * 4 + j] : 0.0f);
      if (RELU) v = fmaxf(v, 0.0f);
      op[j] = v;
    }
    *(float4*)&C[(size_t)row * N + bn + tx * 4] = o;
  }
}

// dual-weight (u rows < UU, i rows >= UU): C = A@B{u,i} + bias{u,i}
template<bool RELU>
__global__ __launch_bounds__(256, 4) void gemm2_k(
    const float* __restrict__ A, const float* __restrict__ Bu,
    const float* __restrict__ Bi, const float* __restrict__ biasu,
    const float* __restrict__ biasi, float* __restrict__ C,
    int N, int K) {
  __shared__ float As[16][68];
  __shared__ float Bs[16][68];
  const int bm = blockIdx.y * 64, bn = blockIdx.x * 64;
  const float* B    = (bm < UU) ? Bu : Bi;
  const float* bias = (bm < UU) ? biasu : biasi;
  float acc[4][4] = {{0.f}};
  gemm_core(A, B, N, K, bm, bn, 0, K, As, Bs, acc);
  const int tx = threadIdx.x & 15, ty = threadIdx.x >> 4;
#pragma unroll
  for (int i = 0; i < 4; ++i) {
    int row = bm + ty * 4 + i;
    float4 o; float* op = (float*)&o;
#pragma unroll
    for (int j = 0; j < 4; ++j) {
      float v = acc[i][j] + bias[bn + tx * 4 + j];
      if (RELU) v = fmaxf(v, 0.0f);
      op[j] = v;
    }
    *(float4*)&C[(size_t)row * N + bn + tx * 4] = o;
  }
}

// dual-weight fused QKV over all 6144 rows: Cb = [3][NTOT][DD]
__global__ __launch_bounds__(256, 4) void gemm_qkv2_k(
    const float* __restrict__ A, const float* __restrict__ Wu,
    const float* __restrict__ Wi, const float* __restrict__ Bu,
    const float* __restrict__ Bi, float* __restrict__ Cb) {
  __shared__ float As[16][68];
  __shared__ float Bs[16][68];
  const int mat = blockIdx.x >> 1;
  const int bn = (blockIdx.x & 1) * 64;
  const int bm = blockIdx.y * 64;
  const float* W    = ((bm < UU) ? Wu : Wi) + (size_t)mat * DD * DD;
  const float* bias = ((bm < UU) ? Bu : Bi) + mat * DD;
  float* C = Cb + (size_t)mat * NTOT * DD;
  float acc[4][4] = {{0.f}};
  gemm_core(A, W, DD, DD, bm, bn, 0, DD, As, Bs, acc);
  const int tx = threadIdx.x & 15, ty = threadIdx.x >> 4;
#pragma unroll
  for (int i = 0; i < 4; ++i) {
    int row = bm + ty * 4 + i;
    float4 o; float* op = (float*)&o;
#pragma unroll
    for (int j = 0; j < 4; ++j) op[j] = acc[i][j] + bias[bn + tx * 4 + j];
    *(float4*)&C[(size_t)row * DD + bn + tx * 4] = o;
  }
}

// raw-proj + blend fused: C = alpha*(A@B + bias) + (1-alpha)*learned
__global__ __launch_bounds__(256, 4) void gemm_blend_k(
    const float* __restrict__ A, const float* __restrict__ B,
    const float* __restrict__ bias, const float* __restrict__ ue,
    const float* __restrict__ ie, const float* __restrict__ alpha_p,
    float* __restrict__ C, int K) {
  __shared__ float As[16][68];
  __shared__ float Bs[16][68];
  const int bm = blockIdx.y * 64, bn = blockIdx.x * 64;
  float acc[4][4] = {{0.f}};
  gemm_core(A, B, DD, K, bm, bn, 0, K, As, Bs, acc);
  const int tx = threadIdx.x & 15, ty = threadIdx.x >> 4;
  float a = alpha_p[0];
#pragma unroll
  for (int i = 0; i < 4; ++i) {
    int row = bm + ty * 4 + i;
    const float* lrn = (row < UU) ? &ue[(size_t)row * DD]
                                  : &ie[(size_t)(row - UU) * DD];
    float4 lv = *(const float4*)&lrn[bn + tx * 4];
    const float* lp = (const float*)&lv;
    float4 o; float* op = (float*)&o;
#pragma unroll
    for (int j = 0; j < 4; ++j)
      op[j] = a * (acc[i][j] + bias[bn + tx * 4 + j]) + (1.0f - a) * lp[j];
    *(float4*)&C[(size_t)row * DD + bn + tx * 4] = o;
  }
}

// gate+PE fused: Cout = Acur + sigmoid(Acur@B + bias) * pe   (no in-place race)
__global__ __launch_bounds__(256, 4) void gemm_gate_k(
    const float* __restrict__ Acur, const float* __restrict__ B,
    const float* __restrict__ bias, const float* __restrict__ pe,
    float* __restrict__ Cout) {
  __shared__ float As[16][68];
  __shared__ float Bs[16][68];
  const int bm = blockIdx.y * 64, bn = blockIdx.x * 64;
  float acc[4][4] = {{0.f}};
  gemm_core(Acur, B, DD, DD, bm, bn, 0, DD, As, Bs, acc);
  const int tx = threadIdx.x & 15, ty = threadIdx.x >> 4;
#pragma unroll
  for (int i = 0; i < 4; ++i) {
    int row = bm + ty * 4 + i;
    float4 cv = *(const float4*)&Acur[(size_t)row * DD + bn + tx * 4];
    float4 pv = *(const float4*)&pe[(size_t)row * DD + bn + tx * 4];
    const float* cp = (const float*)&cv;
    const float* pp = (const float*)&pv;
    float4 o; float* op = (float*)&o;
#pragma unroll
    for (int j = 0; j < 4; ++j) {
      float v = acc[i][j] + bias[bn + tx * 4 + j];
      float g = 1.0f / (1.0f + expf(-v));
      op[j] = cp[j] + g * pp[j];
    }
    *(float4*)&Cout[(size_t)row * DD + bn + tx * 4] = o;
  }
}

// split-K accumulate with fused per-k dinv on B: C += alpha*dinv[i]*(vs @ dinv[k]*B[k])
__global__ __launch_bounds__(256, 4) void gemm_sk_k(
    const float* __restrict__ A, const float* __restrict__ B,
    const float* __restrict__ dinv, const float* __restrict__ alpha_p,
    float* __restrict__ C, int KCH) {
  __shared__ float As[16][68];
  __shared__ float Bs[16][68];
  const int N = DD, K = II;
  const int tid = threadIdx.x;
  const int am = tid >> 2, ak = (tid & 3) * 4;
  const int bk = tid >> 4, bnc = (tid & 15) * 4;
  const int bm = blockIdx.y * 64, bn = blockIdx.x * 64;
  const int kb = blockIdx.z * KCH, ke = kb + KCH;
  const float* Ap = A + (size_t)(bm + am) * K + ak;
  const float* Bp = B + (size_t)bk * N + bn + bnc;
  float4 av = *(const float4*)(Ap + kb);
  float4 bv = *(const float4*)(Bp + (size_t)kb * N);
  const int tx = tid & 15, ty = tid >> 4;
  float acc[4][4] = {{0.f}};
  for (int k0 = kb; k0 < ke; k0 += 16) {
    float ds = dinv[k0 + bk];
    __syncthreads();
    As[ak + 0][am] = av.x; As[ak + 1][am] = av.y;
    As[ak + 2][am] = av.z; As[ak + 3][am] = av.w;
    float4 sb = bv;
    sb.x *= ds; sb.y *= ds; sb.z *= ds; sb.w *= ds;
    *(float4*)&Bs[bk][bnc] = sb;
    __syncthreads();
    if (k0 + 16 < ke) {
      av = *(const float4*)(Ap + k0 + 16);
      bv = *(const float4*)(Bp + (size_t)(k0 + 16) * N);
    }
#pragma unroll
    for (int kq = 0; kq < 16; ++kq) {
      float4 a4 = *(const float4*)&As[kq][ty * 4];
      float4 b4 = *(const float4*)&Bs[kq][tx * 4];
      const float* ap = (const float*)&a4;
      const float* bp = (const float*)&b4;
#pragma unroll
      for (int i = 0; i < 4; ++i)
#pragma unroll
        for (int j = 0; j < 4; ++j)
          acc[i][j] = fmaf(ap[i], bp[j], acc[i][j]);
    }
  }
  float sc = alpha_p[0];
#pragma unroll
  for (int i = 0; i < 4; ++i) {
    int row = bm + ty * 4 + i;
    float rs = dinv[row] * sc;
#pragma unroll
    for (int j = 0; j < 4; ++j)
      atomicAdd(&C[(size_t)row * N + bn + tx * 4 + j], acc[i][j] * rs);
  }
}

// ---------------- top-10 register list insertion (desc, ties -> lower idx) ----
__device__ __forceinline__ void ins10(float (&v)[10], int (&ix)[10], float cv, int ci) {
  if (!((cv > v[9]) || (cv == v[9] && ci < ix[9]))) return;
#pragma unroll
  for (int q = 0; q < 10; ++q) {
    bool b = (cv > v[q]) || (cv == v[q] && ci < ix[q]);
    float ov = v[q]; int oi = ix[q];
    if (b) { v[q] = cv; ix[q] = ci; cv = ov; ci = oi; }
  }
}

// ---------------- top-K partial: per (j-quarter, 32-row tile) -----------------
// v3: NO register prefetch of Ej (round-4/5's ejr[8] was spilled to scratch
// each tile: 534 MB HBM writes/dispatch). Direct global->LDS staging instead.
__global__ __launch_bounds__(256, 3) void topk_part_k(
    const float* __restrict__ E, const float* __restrict__ adj,
    float* __restrict__ topv, int* __restrict__ topi) {
  const int quarter = blockIdx.x;      // 0..3
  const int i0 = blockIdx.y * 32;
  const int jb = quarter * 1536;
  const int tid = threadIdx.x;
  const int a0 = tid & 15;
  const int b0 = tid >> 4;

  __shared__ __align__(16) unsigned char sm[50688];
  float4* Ei4 = (float4*)sm;                  // 32*33 f4 = 16896 B
  float4* Ej4 = (float4*)(sm + 16896);        // 64*33 f4 = 33792 B
  float* dv   = (float*)(sm + 0);             // [32][162]
  int*   di   = (int*)  (sm + 20736);
  float* redv = (float*)(sm + 41472);         // [32][17]
  int*   redi = (int*)  (sm + 43648);
  float* wlv  = (float*)(sm + 45824);         // [32][10]
  int*   wli  = (int*)  (sm + 47104);

  for (int p = 0; p < 4; ++p) {
    int l = tid + p * 256, r = l >> 5, c = l & 31;
    Ei4[r * 33 + c] = ((const float4*)(E + (size_t)(i0 + r) * DD))[c];
  }

  float v0[10], v1[10]; int y0[10], y1[10];
#pragma unroll
  for (int q = 0; q < 10; ++q) { v0[q] = -INFINITY; v1[q] = -INFINITY; y0[q] = 0x7fffffff; y1[q] = 0x7fffffff; }

  const float* arow0 = adj + (size_t)(i0 + a0) * NTOT;
  const float* arow1 = adj + (size_t)(i0 + a0 + 16) * NTOT;

  for (int jt = 0; jt < 24; ++jt) {
    const int jc = jb + jt * 64;
    __syncthreads();
#pragma unroll
    for (int p = 0; p < 8; ++p) {
      int l = tid + p * 256, r = l >> 5, c = l & 31;
      Ej4[r * 33 + c] = ((const float4*)(E + (size_t)(jc + r) * DD))[c];
    }
    __syncthreads();
    float ad0[4], ad1[4];
#pragma unroll
    for (int u = 0; u < 4; ++u) {      // early adj loads (L1/L2), used post-dot
      int jg = jc + b0 + 16 * u;
      ad0[u] = arow0[jg];
      ad1[u] = arow1[jg];
    }
    float d0[4] = {0.f, 0.f, 0.f, 0.f}, d1[4] = {0.f, 0.f, 0.f, 0.f};
#pragma unroll 8
    for (int kq = 0; kq < 32; ++kq) {
      float4 aa = Ei4[a0 * 33 + kq];
      float4 ab = Ei4[(a0 + 16) * 33 + kq];
#pragma unroll
      for (int u = 0; u < 4; ++u) {
        float4 b = Ej4[(b0 + 16 * u) * 33 + kq];
        d0[u] = fmaf(aa.x, b.x, fmaf(aa.y, b.y, fmaf(aa.z, b.z, fmaf(aa.w, b.w, d0[u]))));
        d1[u] = fmaf(ab.x, b.x, fmaf(ab.y, b.y, fmaf(ab.z, b.z, fmaf(ab.w, b.w, d1[u]))));
      }
    }
#pragma unroll
    for (int u = 0; u < 4; ++u) {
      int jg = jc + b0 + 16 * u;
      ins10(v0, y0, 0.5f * d0[u] + 0.5f * ad0[u], jg);
      ins10(v1, y1, 0.5f * d1[u] + 0.5f * ad1[u], jg);
    }
  }

  __syncthreads();
  const int r0 = a0, r1 = a0 + 16;
#pragma unroll
  for (int q = 0; q < 10; ++q) {
    dv[r0 * 162 + b0 * 10 + q] = v0[q];  di[r0 * 162 + b0 * 10 + q] = y0[q];
    dv[r1 * 162 + b0 * 10 + q] = v1[q];  di[r1 * 162 + b0 * 10 + q] = y1[q];
  }
  __syncthreads();

  int p0 = 0, p1 = 0;
  for (int round = 0; round < 10; ++round) {
    float h0 = dv[r0 * 162 + b0 * 10 + p0]; int h0i = di[r0 * 162 + b0 * 10 + p0];
    float h1 = dv[r1 * 162 + b0 * 10 + p1]; int h1i = di[r1 * 162 + b0 * 10 + p1];
    redv[r0 * 17 + b0] = h0; redi[r0 * 17 + b0] = h0i;
    redv[r1 * 17 + b0] = h1; redi[r1 * 17 + b0] = h1i;
    __syncthreads();
    for (int st = 8; st >= 1; st >>= 1) {
      if (b0 < st) {
        float ov = redv[r0 * 17 + b0 + st]; int oi = redi[r0 * 17 + b0 + st];
        if (ov > redv[r0 * 17 + b0] || (ov == redv[r0 * 17 + b0] && oi < redi[r0 * 17 + b0])) {
          redv[r0 * 17 + b0] = ov; redi[r0 * 17 + b0] = oi;
        }
        ov = redv[r1 * 17 + b0 + st]; oi = redi[r1 * 17 + b0 + st];
        if (ov > redv[r1 * 17 + b0] || (ov == redv[r1 * 17 + b0] && oi < redi[r1 * 17 + b0])) {
          redv[r1 * 17 + b0] = ov; redi[r1 * 17 + b0] = oi;
        }
      }
      __syncthreads();
    }
    int w0 = redi[r0 * 17], w1 = redi[r1 * 17];
    if (b0 == 0) {
      wlv[r0 * 10 + round] = redv[r0 * 17]; wli[r0 * 10 + round] = w0;
      wlv[r1 * 10 + round] = redv[r1 * 17]; wli[r1 * 10 + round] = w1;
    }
    if (w0 == h0i) ++p0;
    if (w1 == h1i) ++p1;
    __syncthreads();
  }

  for (int t = tid; t < 320; t += 256) {
    int row = t / 10, q = t - row * 10;
    int gi = i0 + row;
    topv[(size_t)gi * 40 + quarter * 10 + q] = wlv[row * 10 + q];
    topi[(size_t)gi * 40 + quarter * 10 + q] = wli[row * 10 + q];
  }
}

// ---------------- merge 4 quarter-lists + gather SpMM ----------------
__global__ __launch_bounds__(256) void topk_merge_k(
    const float* __restrict__ topv, const int* __restrict__ topi,
    const float* __restrict__ adj, const float* __restrict__ E,
    float* __restrict__ cur) {
  const int i0 = blockIdx.x * 16, tid = threadIdx.x;
  __shared__ int   midx[16][10];
  __shared__ float madj[16][10];
  if (tid < 16) {
    int row = i0 + tid;
    const float* va = topv + (size_t)row * 40;
    const int*   ia = topi + (size_t)row * 40;
    int pp0 = 0, pp1 = 0, pp2 = 0, pp3 = 0;
    for (int q = 0; q < 10; ++q) {
      float bv = va[pp0]; int bi = ia[pp0]; int bq = 0;
      float cv = va[10 + pp1]; int ci = ia[10 + pp1];
      if (cv > bv || (cv == bv && ci < bi)) { bv = cv; bi = ci; bq = 1; }
      cv = va[20 + pp2]; ci = ia[20 + pp2];
      if (cv > bv || (cv == bv && ci < bi)) { bv = cv; bi = ci; bq = 2; }
      cv = va[30 + pp3]; ci = ia[30 + pp3];
      if (cv > bv || (cv == bv && ci < bi)) { bv = cv; bi = ci; bq = 3; }
      if (bq == 0) ++pp0; else if (bq == 1) ++pp1; else if (bq == 2) ++pp2; else ++pp3;
      midx[tid][q] = bi;
      madj[tid][q] = adj[(size_t)row * NTOT + bi];
    }
  }
  __syncthreads();
  int d = tid & 127, hf = tid >> 7;
  for (int rr = 0; rr < 8; ++rr) {
    int r = rr * 2 + hf;
    float acc = 0.f;
#pragma unroll
    for (int w2 = 0; w2 < 10; ++w2) acc += madj[r][w2] * E[(size_t)midx[r][w2] * DD + d];
    cur[(size_t)(i0 + r) * DD + d] = acc;
  }
}

// ---------------- final weighted sum ----------------
__global__ void final_k(const float* __restrict__ x0, const float* __restrict__ x1,
                        const float* __restrict__ x2, float* __restrict__ out) {
  int idx = blockIdx.x * 256 + threadIdx.x;
  if (idx >= NTOT * DD) return;
  float v = x0[idx] + 0.75f * x1[idx] + 0.5f * x2[idx];
  out[idx] = v;
  out[NTOT * DD + idx] = v;
}

// ---------------- flash attention over both halves -------------------------
// 16 q-rows x 64-key tiles per block; keys restricted to the q-row's half.
__global__ __launch_bounds__(256, 3) void attn_k(
    const float* __restrict__ qkv, float* __restrict__ O) {
  const int qb = blockIdx.x * 16;
  const int hoff = blockIdx.y * 32;
  const int koff = (qb >= UU) ? UU : 0;
  const float* Q  = qkv;
  const float* Km = qkv + (size_t)NTOT * DD + (size_t)koff * DD;
  const float* V  = qkv + (size_t)2 * NTOT * DD + (size_t)koff * DD;
  const int tid = threadIdx.x;
  const int r = tid >> 4, g = tid & 15;
  const int jh = g >> 3, d4 = g & 7;
  __shared__ float4 Kt[64 * 9];
  __shared__ float4 Vt[64 * 9];
  __shared__ float  P[16 * 68];

  float4 qr[8];
  const float4* Qp = (const float4*)(Q + (size_t)(qb + r) * DD + hoff);
#pragma unroll
  for (int t = 0; t < 8; ++t) {
    float4 v = Qp[t];
    v.x *= 0.17677669529663687f; v.y *= 0.17677669529663687f;  // 1/sqrt(32)
    v.z *= 0.17677669529663687f; v.w *= 0.17677669529663687f;
    qr[t] = v;
  }
  float m_run = -INFINITY, l_run = 0.f;
  float4 acc = {0.f, 0.f, 0.f, 0.f};

  for (int t0 = 0; t0 < SS; t0 += 64) {
    __syncthreads();
#pragma unroll
    for (int p = 0; p < 2; ++p) {
      int l = tid + p * 256, row = l >> 3, c = l & 7;
      Kt[row * 9 + c] = ((const float4*)(Km + (size_t)(t0 + row) * DD + hoff))[c];
      Vt[row * 9 + c] = ((const float4*)(V  + (size_t)(t0 + row) * DD + hoff))[c];
    }
    __syncthreads();
    float s[4];
#pragma unroll
    for (int q = 0; q < 4; ++q) {
      const float4* Kr = &Kt[(g + 16 * q) * 9];
      float d = 0.f;
#pragma unroll
      for (int t = 0; t < 8; ++t) {
        float4 a = qr[t], b = Kr[t];
        d = fmaf(a.x, b.x, fmaf(a.y, b.y, fmaf(a.z, b.z, fmaf(a.w, b.w, d))));
      }
      s[q] = d;
    }
    float tm = fmaxf(fmaxf(s[0], s[1]), fmaxf(s[2], s[3]));
#pragma unroll
    for (int off = 1; off < 16; off <<= 1) tm = fmaxf(tm, __shfl_xor(tm, off, 64));
    float m_new = fmaxf(m_run, tm);
    float sc = expf(m_run - m_new);
    float ts = 0.f;
#pragma unroll
    for (int q = 0; q < 4; ++q) {
      float p = expf(s[q] - m_new);
      ts += p;
      P[r * 68 + g + 16 * q] = p;
    }
#pragma unroll
    for (int off = 1; off < 16; off <<= 1) ts += __shfl_xor(ts, off, 64);
    l_run = l_run * sc + ts;
    m_run = m_new;
    acc.x *= sc; acc.y *= sc; acc.z *= sc; acc.w *= sc;
    __syncthreads();
    const float* Prow = &P[r * 68 + jh * 32];
#pragma unroll
    for (int jj4 = 0; jj4 < 8; ++jj4) {
      float4 pv = *(const float4*)(Prow + jj4 * 4);
      const float* pp = (const float*)&pv;
#pragma unroll
      for (int c = 0; c < 4; ++c) {
        float4 v4 = Vt[(jh * 32 + jj4 * 4 + c) * 9 + d4];
        acc.x = fmaf(pp[c], v4.x, acc.x);
        acc.y = fmaf(pp[c], v4.y, acc.y);
        acc.z = fmaf(pp[c], v4.z, acc.z);
        acc.w = fmaf(pp[c], v4.w, acc.w);
      }
    }
  }
  acc.x += __shfl_xor(acc.x, 8, 64);
  acc.y += __shfl_xor(acc.y, 8, 64);
  acc.z += __shfl_xor(acc.z, 8, 64);
  acc.w += __shfl_xor(acc.w, 8, 64);
  if (jh == 0) {
    float inv = 1.0f / l_run;
    float4 o = {acc.x * inv, acc.y * inv, acc.z * inv, acc.w * inv};
    *(float4*)(O + (size_t)(qb + r) * DD + hoff + d4 * 4) = o;
  }
}

// ---------------- residual + LayerNorm, dual-param over 6144 rows ----------
__global__ void add_ln2_k(const float* __restrict__ X, const float* __restrict__ Y,
                          const float* __restrict__ gu, const float* __restrict__ bu,
                          const float* __restrict__ gi, const float* __restrict__ bi,
                          float* __restrict__ Out) {
  int row = blockIdx.x, tid = threadIdx.x;
  const float* g = (row < UU) ? gu : gi;
  const float* b = (row < UU) ? bu : bi;
  __shared__ float red[128];
  float v = X[(size_t)row * DD + tid] + Y[(size_t)row * DD + tid];
  red[tid] = v; __syncthreads();
  for (int st = 64; st > 0; st >>= 1) { if (tid < st) red[tid] += red[tid + st]; __syncthreads(); }
  float mean = red[0] * (1.0f / DD); __syncthreads();
  float d = v - mean;
  red[tid] = d * d; __syncthreads();
  for (int st = 64; st > 0; st >>= 1) { if (tid < st) red[tid] += red[tid + st]; __syncthreads(); }
  float var = red[0] * (1.0f / DD); __syncthreads();
  Out[(size_t)row * DD + tid] = d * (1.0f / sqrtf(var + 1e-5f)) * g[tid] + b[tid];
}

extern "C" void kernel_launch(void* const* d_in, const int* in_sizes, int n_in,
                              void* d_out, int out_size, void* d_ws, size_t ws_size,
                              hipStream_t stream) {
  (void)in_sizes; (void)n_in; (void)out_size; (void)ws_size;
  const float* adj       = (const float*)d_in[0];
  const float* raw_nodes = (const float*)d_in[1];
  const float* proj_w    = (const float*)d_in[2];
  const float* proj_b    = (const float*)d_in[3];
  const float* user_emb  = (const float*)d_in[4];
  const float* item_emb  = (const float*)d_in[5];
  const float* vs        = (const float*)d_in[6];
  const float* alpha_p   = (const float*)d_in[7];
  const float* pgw       = (const float*)d_in[8];
  const float* pgb       = (const float*)d_in[9];
  const float* uaw = (const float*)d_in[10];
  const float* uab = (const float*)d_in[11];
  const float* uw1 = (const float*)d_in[12];
  const float* ub1 = (const float*)d_in[13];
  const float* uw2 = (const float*)d_in[14];
  const float* ub2 = (const float*)d_in[15];
  const float* ulg = (const float*)d_in[16];
  const float* ulb = (const float*)d_in[17];
  const float* iaw = (const float*)d_in[18];
  const float* iab = (const float*)d_in[19];
  const float* iw1 = (const float*)d_in[20];
  const float* ib1 = (const float*)d_in[21];
  const float* iw2 = (const float*)d_in[22];
  const float* ib2 = (const float*)d_in[23];
  const float* ilg = (const float*)d_in[24];
  const float* ilb = (const float*)d_in[25];

  float* w = (float*)d_ws;
  float* pe   = w; w += (size_t)NTOT * DD;
  float* x0   = w; w += (size_t)NTOT * DD;
  float* x1   = w; w += (size_t)NTOT * DD;
  float* x2   = w; w += (size_t)NTOT * DD;
  float* cur  = w; w += (size_t)NTOT * DD;
  float* curg = w; w += (size_t)NTOT * DD;
  float* qkv  = w; w += (size_t)3 * NTOT * DD;
  float* xl   = w; w += (size_t)NTOT * DD;
  float* f2   = w; w += (size_t)NTOT * DD;
  float* t1   = w; w += (size_t)NTOT * DFF2;
  float* dinv = w; w += 4096;
  float* ao   = t1;                          // alias: dead before ffn1 writes t1
  float* topv = qkv;                         // alias: dead before qkv written
  int*   topi = (int*)(qkv + (size_t)NTOT * DD);

  pe_k<<<(NTOT * 64 + 255) / 256, 256, 0, stream>>>(pe);
  dinv_k<<<II, 256, 0, stream>>>(vs, dinv);
  gemm_blend_k<<<dim3(2, NTOT / 64), 256, 0, stream>>>(
      raw_nodes, proj_w, proj_b, user_emb, item_emb, alpha_p, x0, 1280);

  float* xs[3] = {x0, x1, x2};
  for (int b = 0; b < 2; ++b) {
    const float* prev = xs[b];
    float* outb = xs[b + 1];
    topk_part_k<<<dim3(4, 192), 256, 0, stream>>>(prev, adj, topv, topi);
    topk_merge_k<<<NTOT / 16, 256, 0, stream>>>(topv, topi, adj, prev, cur);
    // cur[U:] += alpha * dinv_i * (vs @ (dinv_j * prev[U:]))  (split-K x4)
    gemm_sk_k<<<dim3(2, II / 64, 4), 256, 0, stream>>>(
        vs, prev + (size_t)UU * DD, dinv, alpha_p, cur + (size_t)UU * DD, 768);
    // curg = cur + sigmoid(cur@pgw + pgb) * pe
    gemm_gate_k<<<dim3(2, NTOT / 64), 256, 0, stream>>>(cur, pgw, pgb, pe, curg);
    // fused 6144-row encoder (u weights for rows<U, i weights otherwise)
    gemm_qkv2_k<<<dim3(6, NTOT / 64), 256, 0, stream>>>(curg, uaw, iaw, uab, iab, qkv);
    attn_k<<<dim3(NTOT / 16, HH), 256, 0, stream>>>(qkv, ao);
    gemm2_k<false><<<dim3(2, NTOT / 64), 256, 0, stream>>>(
        ao, uaw + 3 * DD * DD, iaw + 3 * DD * DD, uab + 3 * DD, iab + 3 * DD, f2, DD, DD);
    add_ln2_k<<<NTOT, 128, 0, stream>>>(curg, f2, ulg, ulb, ilg, ilb, xl);
    gemm2_k<true ><<<dim3(8, NTOT / 64), 256, 0, stream>>>(
        xl, uw1, iw1, ub1, ib1, t1, DFF2, DD);
    gemm2_k<false><<<dim3(2, NTOT / 64), 256, 0, stream>>>(
        t1, uw2, iw2, ub2, ib2, f2, DD, DFF2);
    add_ln2_k<<<NTOT, 128, 0, stream>>>(xl, f2, ulg + DD, ulb + DD, ilg + DD, ilb + DD, outb);
  }
  final_k<<<(NTOT * DD + 255) / 256, 256, 0, stream>>>(x0, x1, x2, (float*)d_out);
}

// Round 7
// 1830.053 us; speedup vs baseline: 7.7286x; 1.0725x over previous
//
#include <hip/hip_runtime.h>
#include <math.h>

#define NTOT 6144
#define UU   3072
#define II   3072
#define DD   128
#define SS   3072
#define DFF2 512
#define HH   4

// ---------------- sinusoidal PE table ----------------
__global__ void pe_k(float* __restrict__ pe) {
  int idx = blockIdx.x * 256 + threadIdx.x;
  if (idx >= NTOT * 64) return;
  int pos = idx >> 6, j = idx & 63;
  float ex = (2.0f * (float)j) * (-0.07195578415606394f);  // -ln(10000)/128
  float dv = expf(ex);
  float ang = (float)pos * dv;
  pe[(size_t)pos * DD + 2 * j]     = sinf(ang);
  pe[(size_t)pos * DD + 2 * j + 1] = cosf(ang);
}

// ---------------- dinv = (rowsum(vs)+eps)^-0.5 ----------------
__global__ void dinv_k(const float* __restrict__ vs, float* __restrict__ dinv) {
  int i = blockIdx.x, tid = threadIdx.x;
  __shared__ float red[256];
  float s = 0.f;
  const float* row = vs + (size_t)i * II;
  for (int j = tid; j < II; j += 256) s += row[j];
  red[tid] = s; __syncthreads();
  for (int st = 128; st > 0; st >>= 1) { if (tid < st) red[tid] += red[tid + st]; __syncthreads(); }
  if (tid == 0) dinv[i] = 1.0f / sqrtf(red[0] + 1e-7f);
}

// ---------------- shared GEMM core (64x64 tile, f4 LDS reads, prefetch) -------
__device__ __forceinline__ void gemm_core(
    const float* __restrict__ A, const float* __restrict__ B,
    int N, int K, int bm, int bn, int k0beg, int k0end,
    float (*As)[68], float (*Bs)[68], float (&acc)[4][4]) {
  const int tid = threadIdx.x;
  const int am = tid >> 2, ak = (tid & 3) * 4;
  const int bk = tid >> 4, bnc = (tid & 15) * 4;
  const float* Ap = A + (size_t)(bm + am) * K + ak;
  const float* Bp = B + (size_t)bk * N + bn + bnc;
  float4 av = *(const float4*)(Ap + k0beg);
  float4 bv = *(const float4*)(Bp + (size_t)k0beg * N);
  const int tx = tid & 15, ty = tid >> 4;
  for (int k0 = k0beg; k0 < k0end; k0 += 16) {
    __syncthreads();
    As[ak + 0][am] = av.x; As[ak + 1][am] = av.y;
    As[ak + 2][am] = av.z; As[ak + 3][am] = av.w;
    *(float4*)&Bs[bk][bnc] = bv;
    __syncthreads();
    if (k0 + 16 < k0end) {
      av = *(const float4*)(Ap + k0 + 16);
      bv = *(const float4*)(Bp + (size_t)(k0 + 16) * N);
    }
#pragma unroll
    for (int kq = 0; kq < 16; ++kq) {
      float4 a4 = *(const float4*)&As[kq][ty * 4];
      float4 b4 = *(const float4*)&Bs[kq][tx * 4];
      const float* ap = (const float*)&a4;
      const float* bp = (const float*)&b4;
#pragma unroll
      for (int i = 0; i < 4; ++i)
#pragma unroll
        for (int j = 0; j < 4; ++j)
          acc[i][j] = fmaf(ap[i], bp[j], acc[i][j]);
    }
  }
}

// plain: C = A@B + bias (optional relu)
template<bool RELU>
__global__ __launch_bounds__(256, 4) void gemm_k(
    const float* __restrict__ A, const float* __restrict__ B,
    const float* __restrict__ bias, float* __restrict__ C,
    int M, int N, int K) {
  __shared__ float As[16][68];
  __shared__ float Bs[16][68];
  const int bm = blockIdx.y * 64, bn = blockIdx.x * 64;
  float acc[4][4] = {{0.f}};
  gemm_core(A, B, N, K, bm, bn, 0, K, As, Bs, acc);
  const int tx = threadIdx.x & 15, ty = threadIdx.x >> 4;
#pragma unroll
  for (int i = 0; i < 4; ++i) {
    int row = bm + ty * 4 + i;
    float4 o; float* op = (float*)&o;
#pragma unroll
    for (int j = 0; j < 4; ++j) {
      float v = acc[i][j] + (bias ? bias[bn + tx * 4 + j] : 0.0f);
      if (RELU) v = fmaxf(v, 0.0f);
      op[j] = v;
    }
    *(float4*)&C[(size_t)row * N + bn + tx * 4] = o;
  }
}

// dual-weight (u rows < UU, i rows >= UU)
template<bool RELU>
__global__ __launch_bounds__(256, 4) void gemm2_k(
    const float* __restrict__ A, const float* __restrict__ Bu,
    const float* __restrict__ Bi, const float* __restrict__ biasu,
    const float* __restrict__ biasi, float* __restrict__ C,
    int N, int K) {
  __shared__ float As[16][68];
  __shared__ float Bs[16][68];
  const int bm = blockIdx.y * 64, bn = blockIdx.x * 64;
  const float* B    = (bm < UU) ? Bu : Bi;
  const float* bias = (bm < UU) ? biasu : biasi;
  float acc[4][4] = {{0.f}};
  gemm_core(A, B, N, K, bm, bn, 0, K, As, Bs, acc);
  const int tx = threadIdx.x & 15, ty = threadIdx.x >> 4;
#pragma unroll
  for (int i = 0; i < 4; ++i) {
    int row = bm + ty * 4 + i;
    float4 o; float* op = (float*)&o;
#pragma unroll
    for (int j = 0; j < 4; ++j) {
      float v = acc[i][j] + bias[bn + tx * 4 + j];
      if (RELU) v = fmaxf(v, 0.0f);
      op[j] = v;
    }
    *(float4*)&C[(size_t)row * N + bn + tx * 4] = o;
  }
}

// dual-weight fused QKV over all 6144 rows: Cb = [3][NTOT][DD]
__global__ __launch_bounds__(256, 4) void gemm_qkv2_k(
    const float* __restrict__ A, const float* __restrict__ Wu,
    const float* __restrict__ Wi, const float* __restrict__ Bu,
    const float* __restrict__ Bi, float* __restrict__ Cb) {
  __shared__ float As[16][68];
  __shared__ float Bs[16][68];
  const int mat = blockIdx.x >> 1;
  const int bn = (blockIdx.x & 1) * 64;
  const int bm = blockIdx.y * 64;
  const float* W    = ((bm < UU) ? Wu : Wi) + (size_t)mat * DD * DD;
  const float* bias = ((bm < UU) ? Bu : Bi) + mat * DD;
  float* C = Cb + (size_t)mat * NTOT * DD;
  float acc[4][4] = {{0.f}};
  gemm_core(A, W, DD, DD, bm, bn, 0, DD, As, Bs, acc);
  const int tx = threadIdx.x & 15, ty = threadIdx.x >> 4;
#pragma unroll
  for (int i = 0; i < 4; ++i) {
    int row = bm + ty * 4 + i;
    float4 o; float* op = (float*)&o;
#pragma unroll
    for (int j = 0; j < 4; ++j) op[j] = acc[i][j] + bias[bn + tx * 4 + j];
    *(float4*)&C[(size_t)row * DD + bn + tx * 4] = o;
  }
}

// raw-proj + blend fused
__global__ __launch_bounds__(256, 4) void gemm_blend_k(
    const float* __restrict__ A, const float* __restrict__ B,
    const float* __restrict__ bias, const float* __restrict__ ue,
    const float* __restrict__ ie, const float* __restrict__ alpha_p,
    float* __restrict__ C, int K) {
  __shared__ float As[16][68];
  __shared__ float Bs[16][68];
  const int bm = blockIdx.y * 64, bn = blockIdx.x * 64;
  float acc[4][4] = {{0.f}};
  gemm_core(A, B, DD, K, bm, bn, 0, K, As, Bs, acc);
  const int tx = threadIdx.x & 15, ty = threadIdx.x >> 4;
  float a = alpha_p[0];
#pragma unroll
  for (int i = 0; i < 4; ++i) {
    int row = bm + ty * 4 + i;
    const float* lrn = (row < UU) ? &ue[(size_t)row * DD]
                                  : &ie[(size_t)(row - UU) * DD];
    float4 lv = *(const float4*)&lrn[bn + tx * 4];
    const float* lp = (const float*)&lv;
    float4 o; float* op = (float*)&o;
#pragma unroll
    for (int j = 0; j < 4; ++j)
      op[j] = a * (acc[i][j] + bias[bn + tx * 4 + j]) + (1.0f - a) * lp[j];
    *(float4*)&C[(size_t)row * DD + bn + tx * 4] = o;
  }
}

// gate+PE fused: Cout = Acur + sigmoid(Acur@B + bias) * pe
__global__ __launch_bounds__(256, 4) void gemm_gate_k(
    const float* __restrict__ Acur, const float* __restrict__ B,
    const float* __restrict__ bias, const float* __restrict__ pe,
    float* __restrict__ Cout) {
  __shared__ float As[16][68];
  __shared__ float Bs[16][68];
  const int bm = blockIdx.y * 64, bn = blockIdx.x * 64;
  float acc[4][4] = {{0.f}};
  gemm_core(Acur, B, DD, DD, bm, bn, 0, DD, As, Bs, acc);
  const int tx = threadIdx.x & 15, ty = threadIdx.x >> 4;
#pragma unroll
  for (int i = 0; i < 4; ++i) {
    int row = bm + ty * 4 + i;
    float4 cv = *(const float4*)&Acur[(size_t)row * DD + bn + tx * 4];
    float4 pv = *(const float4*)&pe[(size_t)row * DD + bn + tx * 4];
    const float* cp = (const float*)&cv;
    const float* pp = (const float*)&pv;
    float4 o; float* op = (float*)&o;
#pragma unroll
    for (int j = 0; j < 4; ++j) {
      float v = acc[i][j] + bias[bn + tx * 4 + j];
      float g = 1.0f / (1.0f + expf(-v));
      op[j] = cp[j] + g * pp[j];
    }
    *(float4*)&Cout[(size_t)row * DD + bn + tx * 4] = o;
  }
}

// split-K accumulate with fused dinv scaling
__global__ __launch_bounds__(256, 4) void gemm_sk_k(
    const float* __restrict__ A, const float* __restrict__ B,
    const float* __restrict__ dinv, const float* __restrict__ alpha_p,
    float* __restrict__ C, int KCH) {
  __shared__ float As[16][68];
  __shared__ float Bs[16][68];
  const int N = DD, K = II;
  const int tid = threadIdx.x;
  const int am = tid >> 2, ak = (tid & 3) * 4;
  const int bk = tid >> 4, bnc = (tid & 15) * 4;
  const int bm = blockIdx.y * 64, bn = blockIdx.x * 64;
  const int kb = blockIdx.z * KCH, ke = kb + KCH;
  const float* Ap = A + (size_t)(bm + am) * K + ak;
  const float* Bp = B + (size_t)bk * N + bn + bnc;
  float4 av = *(const float4*)(Ap + kb);
  float4 bv = *(const float4*)(Bp + (size_t)kb * N);
  const int tx = tid & 15, ty = tid >> 4;
  float acc[4][4] = {{0.f}};
  for (int k0 = kb; k0 < ke; k0 += 16) {
    float ds = dinv[k0 + bk];
    __syncthreads();
    As[ak + 0][am] = av.x; As[ak + 1][am] = av.y;
    As[ak + 2][am] = av.z; As[ak + 3][am] = av.w;
    float4 sb = bv;
    sb.x *= ds; sb.y *= ds; sb.z *= ds; sb.w *= ds;
    *(float4*)&Bs[bk][bnc] = sb;
    __syncthreads();
    if (k0 + 16 < ke) {
      av = *(const float4*)(Ap + k0 + 16);
      bv = *(const float4*)(Bp + (size_t)(k0 + 16) * N);
    }
#pragma unroll
    for (int kq = 0; kq < 16; ++kq) {
      float4 a4 = *(const float4*)&As[kq][ty * 4];
      float4 b4 = *(const float4*)&Bs[kq][tx * 4];
      const float* ap = (const float*)&a4;
      const float* bp = (const float*)&b4;
#pragma unroll
      for (int i = 0; i < 4; ++i)
#pragma unroll
        for (int j = 0; j < 4; ++j)
          acc[i][j] = fmaf(ap[i], bp[j], acc[i][j]);
    }
  }
  float sc = alpha_p[0];
#pragma unroll
  for (int i = 0; i < 4; ++i) {
    int row = bm + ty * 4 + i;
    float rs = dinv[row] * sc;
#pragma unroll
    for (int j = 0; j < 4; ++j)
      atomicAdd(&C[(size_t)row * N + bn + tx * 4 + j], acc[i][j] * rs);
  }
}

// ------------- packed u64 sort key: val desc, idx asc on ties ---------------
__device__ __forceinline__ unsigned long long packsc(float v, int idx) {
  unsigned int b = __float_as_uint(v);
  b ^= (b & 0x80000000u) ? 0xFFFFFFFFu : 0x80000000u;  // order-preserving
  return ((unsigned long long)b << 32) | (unsigned int)(0xFFFFFFFFu ^ (unsigned int)idx);
}

__device__ __forceinline__ void ins10u(unsigned long long (&v)[10], unsigned long long c) {
  if (c <= v[9]) return;
#pragma unroll
  for (int q = 0; q < 10; ++q) {
    unsigned long long ov = v[q];
    if (c > ov) { v[q] = c; c = ov; }
  }
}

__device__ __forceinline__ unsigned long long shflx_u64(unsigned long long v, int off) {
  unsigned int lo = (unsigned int)v, hi = (unsigned int)(v >> 32);
  lo = __shfl_xor(lo, off, 64);
  hi = __shfl_xor(hi, off, 64);
  return ((unsigned long long)hi << 32) | lo;
}

// ---------------- top-K partial v5: 64x128 tile, 4x8 per thread -------------
// scores = 0.5*E_i.E_j + 0.5*adj[i][j] over one j-eighth (768 cols, 6 tiles).
// Per-row top-10 merged in-wave (16-lane shuffle merge), written as u64 keys.
__global__ __launch_bounds__(256, 2) void topk_part_k(
    const float* __restrict__ E, const float* __restrict__ adj,
    unsigned long long* __restrict__ top8) {
  const int eighth = blockIdx.x;            // 0..7
  const int i0 = blockIdx.y * 64;
  const int jb = eighth * 768;
  const int tid = threadIdx.x;
  const int a = tid >> 4;                   // i-group: rows a+16m, m=0..3
  const int b = tid & 15;                   // j-group: cols b+16u, u=0..7

  __shared__ float4 Eis[64 * 17];           // 17.4 KB (k-half 64 = 16 f4, pad 17)
  __shared__ float4 Ejs[128 * 17];          // 34.8 KB
  const float4* E4 = (const float4*)E;

  unsigned long long lst[4][10];
#pragma unroll
  for (int m = 0; m < 4; ++m)
#pragma unroll
    for (int q = 0; q < 10; ++q) lst[m][q] = 0ULL;

  for (int jt = 0; jt < 6; ++jt) {
    const int jc = jb + jt * 128;
    float acc[4][8];
#pragma unroll
    for (int m = 0; m < 4; ++m)
#pragma unroll
      for (int u = 0; u < 8; ++u) acc[m][u] = 0.f;

    for (int kh = 0; kh < 2; ++kh) {
      __syncthreads();
#pragma unroll
      for (int p = 0; p < 4; ++p) {
        int l = tid + p * 256, row = l >> 4, c = l & 15;
        Eis[row * 17 + c] = E4[(size_t)(i0 + row) * 32 + kh * 16 + c];
      }
#pragma unroll
      for (int p = 0; p < 8; ++p) {
        int l = tid + p * 256, row = l >> 4, c = l & 15;
        Ejs[row * 17 + c] = E4[(size_t)(jc + row) * 32 + kh * 16 + c];
      }
      __syncthreads();
#pragma unroll 4
      for (int kq = 0; kq < 16; ++kq) {
        float4 a0 = Eis[a * 17 + kq];
        float4 a1 = Eis[(a + 16) * 17 + kq];
        float4 a2 = Eis[(a + 32) * 17 + kq];
        float4 a3 = Eis[(a + 48) * 17 + kq];
#pragma unroll
        for (int u = 0; u < 8; ++u) {
          float4 bf = Ejs[(b + 16 * u) * 17 + kq];
          acc[0][u] = fmaf(a0.x, bf.x, fmaf(a0.y, bf.y, fmaf(a0.z, bf.z, fmaf(a0.w, bf.w, acc[0][u]))));
          acc[1][u] = fmaf(a1.x, bf.x, fmaf(a1.y, bf.y, fmaf(a1.z, bf.z, fmaf(a1.w, bf.w, acc[1][u]))));
          acc[2][u] = fmaf(a2.x, bf.x, fmaf(a2.y, bf.y, fmaf(a2.z, bf.z, fmaf(a2.w, bf.w, acc[2][u]))));
          acc[3][u] = fmaf(a3.x, bf.x, fmaf(a3.y, bf.y, fmaf(a3.z, bf.z, fmaf(a3.w, bf.w, acc[3][u]))));
        }
      }
    }
    // scores + candidate insertion
#pragma unroll
    for (int m = 0; m < 4; ++m) {
      const float* ar = adj + (size_t)(i0 + a + 16 * m) * NTOT + jc + b;
#pragma unroll
      for (int u = 0; u < 8; ++u) {
        float sc = 0.5f * acc[m][u] + 0.5f * ar[16 * u];
        ins10u(lst[m], packsc(sc, jc + b + 16 * u));
      }
    }
  }

  // in-wave merge: each 16-lane group (fixed a) merges its 16 lists per row.
#pragma unroll
  for (int m = 0; m < 4; ++m) {
    unsigned long long ow[10];
#pragma unroll
    for (int round = 0; round < 10; ++round) {
      unsigned long long h = lst[m][0];
      unsigned long long w = h;
#pragma unroll
      for (int off = 1; off < 16; off <<= 1) {
        unsigned long long o = shflx_u64(w, off);
        if (o > w) w = o;
      }
      ow[round] = w;
      if (h == w) {
#pragma unroll
        for (int q = 0; q < 9; ++q) lst[m][q] = lst[m][q + 1];
      }
    }
    if (b == 0) {
      int grow = i0 + a + 16 * m;
#pragma unroll
      for (int q = 0; q < 10; ++q)
        top8[(size_t)grow * 80 + eighth * 10 + q] = ow[q];
    }
  }
}

// ---------------- merge 8 eighth-lists + gather SpMM ----------------
__global__ __launch_bounds__(256) void topk_merge_k(
    const unsigned long long* __restrict__ top8,
    const float* __restrict__ adj, const float* __restrict__ E,
    float* __restrict__ cur) {
  const int i0 = blockIdx.x * 16, tid = threadIdx.x;
  __shared__ int   midx[16][10];
  __shared__ float madj[16][10];
  if (tid < 16) {
    int row = i0 + tid;
    const unsigned long long* L = top8 + (size_t)row * 80;
    int p[8] = {0, 0, 0, 0, 0, 0, 0, 0};
    for (int q = 0; q < 10; ++q) {
      unsigned long long best = 0ULL; int be = 0;
#pragma unroll
      for (int e = 0; e < 8; ++e) {
        unsigned long long h = (p[e] < 10) ? L[e * 10 + p[e]] : 0ULL;
        if (h > best) { best = h; be = e; }
      }
#pragma unroll
      for (int e = 0; e < 8; ++e) p[e] += (e == be) ? 1 : 0;
      int idx = (int)(0xFFFFFFFFu ^ (unsigned int)best);
      midx[tid][q] = idx;
      madj[tid][q] = adj[(size_t)row * NTOT + idx];
    }
  }
  __syncthreads();
  int d = tid & 127, hf = tid >> 7;
  for (int rr = 0; rr < 8; ++rr) {
    int r = rr * 2 + hf;
    float acc = 0.f;
#pragma unroll
    for (int w2 = 0; w2 < 10; ++w2) acc += madj[r][w2] * E[(size_t)midx[r][w2] * DD + d];
    cur[(size_t)(i0 + r) * DD + d] = acc;
  }
}

// ---------------- final weighted sum ----------------
__global__ void final_k(const float* __restrict__ x0, const float* __restrict__ x1,
                        const float* __restrict__ x2, float* __restrict__ out) {
  int idx = blockIdx.x * 256 + threadIdx.x;
  if (idx >= NTOT * DD) return;
  float v = x0[idx] + 0.75f * x1[idx] + 0.5f * x2[idx];
  out[idx] = v;
  out[NTOT * DD + idx] = v;
}

// ---------------- flash attention v2: 2 q-rows/thread, 32 rows/block --------
__global__ __launch_bounds__(256, 3) void attn_k(
    const float* __restrict__ qkv, float* __restrict__ O) {
  const int qb = blockIdx.x * 32;
  const int hoff = blockIdx.y * 32;
  const int koff = (qb >= UU) ? UU : 0;
  const float* Q  = qkv;
  const float* Km = qkv + (size_t)NTOT * DD + (size_t)koff * DD;
  const float* V  = qkv + (size_t)2 * NTOT * DD + (size_t)koff * DD;
  const int tid = threadIdx.x;
  const int r = tid >> 4, g = tid & 15;
  const int jh = g >> 3, d4 = g & 7;
  __shared__ float4 Kt[64 * 9];
  __shared__ float4 Vt[64 * 9];
  __shared__ float  P[32 * 68];

  float4 q0[8], q1[8];
  const float4* Qp0 = (const float4*)(Q + (size_t)(qb + r) * DD + hoff);
  const float4* Qp1 = (const float4*)(Q + (size_t)(qb + r + 16) * DD + hoff);
#pragma unroll
  for (int t = 0; t < 8; ++t) {
    float4 v = Qp0[t];
    v.x *= 0.17677669529663687f; v.y *= 0.17677669529663687f;
    v.z *= 0.17677669529663687f; v.w *= 0.17677669529663687f;
    q0[t] = v;
    v = Qp1[t];
    v.x *= 0.17677669529663687f; v.y *= 0.17677669529663687f;
    v.z *= 0.17677669529663687f; v.w *= 0.17677669529663687f;
    q1[t] = v;
  }
  float m0 = -INFINITY, l0 = 0.f, m1 = -INFINITY, l1 = 0.f;
  float4 acc0 = {0.f, 0.f, 0.f, 0.f}, acc1 = {0.f, 0.f, 0.f, 0.f};

  for (int t0 = 0; t0 < SS; t0 += 64) {
    __syncthreads();
#pragma unroll
    for (int p = 0; p < 2; ++p) {
      int l = tid + p * 256, row = l >> 3, c = l & 7;
      Kt[row * 9 + c] = ((const float4*)(Km + (size_t)(t0 + row) * DD + hoff))[c];
      Vt[row * 9 + c] = ((const float4*)(V  + (size_t)(t0 + row) * DD + hoff))[c];
    }
    __syncthreads();
    float s0[4], s1[4];
#pragma unroll
    for (int u = 0; u < 4; ++u) {
      const float4* Kr = &Kt[(g + 16 * u) * 9];
      float d0 = 0.f, d1 = 0.f;
#pragma unroll
      for (int t = 0; t < 8; ++t) {
        float4 kb = Kr[t];
        float4 a0 = q0[t], a1 = q1[t];
        d0 = fmaf(a0.x, kb.x, fmaf(a0.y, kb.y, fmaf(a0.z, kb.z, fmaf(a0.w, kb.w, d0))));
        d1 = fmaf(a1.x, kb.x, fmaf(a1.y, kb.y, fmaf(a1.z, kb.z, fmaf(a1.w, kb.w, d1))));
      }
      s0[u] = d0; s1[u] = d1;
    }
    float tm0 = fmaxf(fmaxf(s0[0], s0[1]), fmaxf(s0[2], s0[3]));
    float tm1 = fmaxf(fmaxf(s1[0], s1[1]), fmaxf(s1[2], s1[3]));
#pragma unroll
    for (int off = 1; off < 16; off <<= 1) {
      tm0 = fmaxf(tm0, __shfl_xor(tm0, off, 64));
      tm1 = fmaxf(tm1, __shfl_xor(tm1, off, 64));
    }
    float n0 = fmaxf(m0, tm0), n1 = fmaxf(m1, tm1);
    float sc0 = expf(m0 - n0), sc1 = expf(m1 - n1);
    float ts0 = 0.f, ts1 = 0.f;
#pragma unroll
    for (int u = 0; u < 4; ++u) {
      float p0 = expf(s0[u] - n0), p1 = expf(s1[u] - n1);
      ts0 += p0; ts1 += p1;
      P[r * 68 + g + 16 * u] = p0;
      P[(r + 16) * 68 + g + 16 * u] = p1;
    }
#pragma unroll
    for (int off = 1; off < 16; off <<= 1) {
      ts0 += __shfl_xor(ts0, off, 64);
      ts1 += __shfl_xor(ts1, off, 64);
    }
    l0 = l0 * sc0 + ts0; m0 = n0;
    l1 = l1 * sc1 + ts1; m1 = n1;
    acc0.x *= sc0; acc0.y *= sc0; acc0.z *= sc0; acc0.w *= sc0;
    acc1.x *= sc1; acc1.y *= sc1; acc1.z *= sc1; acc1.w *= sc1;
    __syncthreads();
    const float* Pr0 = &P[r * 68 + jh * 32];
    const float* Pr1 = &P[(r + 16) * 68 + jh * 32];
#pragma unroll
    for (int jj4 = 0; jj4 < 8; ++jj4) {
      float4 pv0 = *(const float4*)(Pr0 + jj4 * 4);
      float4 pv1 = *(const float4*)(Pr1 + jj4 * 4);
      const float* pp0 = (const float*)&pv0;
      const float* pp1 = (const float*)&pv1;
#pragma unroll
      for (int c = 0; c < 4; ++c) {
        float4 v4 = Vt[(jh * 32 + jj4 * 4 + c) * 9 + d4];
        acc0.x = fmaf(pp0[c], v4.x, acc0.x);
        acc0.y = fmaf(pp0[c], v4.y, acc0.y);
        acc0.z = fmaf(pp0[c], v4.z, acc0.z);
        acc0.w = fmaf(pp0[c], v4.w, acc0.w);
        acc1.x = fmaf(pp1[c], v4.x, acc1.x);
        acc1.y = fmaf(pp1[c], v4.y, acc1.y);
        acc1.z = fmaf(pp1[c], v4.z, acc1.z);
        acc1.w = fmaf(pp1[c], v4.w, acc1.w);
      }
    }
  }
  acc0.x += __shfl_xor(acc0.x, 8, 64);
  acc0.y += __shfl_xor(acc0.y, 8, 64);
  acc0.z += __shfl_xor(acc0.z, 8, 64);
  acc0.w += __shfl_xor(acc0.w, 8, 64);
  acc1.x += __shfl_xor(acc1.x, 8, 64);
  acc1.y += __shfl_xor(acc1.y, 8, 64);
  acc1.z += __shfl_xor(acc1.z, 8, 64);
  acc1.w += __shfl_xor(acc1.w, 8, 64);
  if (jh == 0) {
    float i0v = 1.0f / l0, i1v = 1.0f / l1;
    float4 o0 = {acc0.x * i0v, acc0.y * i0v, acc0.z * i0v, acc0.w * i0v};
    float4 o1 = {acc1.x * i1v, acc1.y * i1v, acc1.z * i1v, acc1.w * i1v};
    *(float4*)(O + (size_t)(qb + r) * DD + hoff + d4 * 4) = o0;
    *(float4*)(O + (size_t)(qb + r + 16) * DD + hoff + d4 * 4) = o1;
  }
}

// ---------------- residual + LayerNorm, dual-param over 6144 rows ----------
__global__ void add_ln2_k(const float* __restrict__ X, const float* __restrict__ Y,
                          const float* __restrict__ gu, const float* __restrict__ bu,
                          const float* __restrict__ gi, const float* __restrict__ bi,
                          float* __restrict__ Out) {
  int row = blockIdx.x, tid = threadIdx.x;
  const float* g = (row < UU) ? gu : gi;
  const float* b = (row < UU) ? bu : bi;
  __shared__ float red[128];
  float v = X[(size_t)row * DD + tid] + Y[(size_t)row * DD + tid];
  red[tid] = v; __syncthreads();
  for (int st = 64; st > 0; st >>= 1) { if (tid < st) red[tid] += red[tid + st]; __syncthreads(); }
  float mean = red[0] * (1.0f / DD); __syncthreads();
  float d = v - mean;
  red[tid] = d * d; __syncthreads();
  for (int st = 64; st > 0; st >>= 1) { if (tid < st) red[tid] += red[tid + st]; __syncthreads(); }
  float var = red[0] * (1.0f / DD); __syncthreads();
  Out[(size_t)row * DD + tid] = d * (1.0f / sqrtf(var + 1e-5f)) * g[tid] + b[tid];
}

extern "C" void kernel_launch(void* const* d_in, const int* in_sizes, int n_in,
                              void* d_out, int out_size, void* d_ws, size_t ws_size,
                              hipStream_t stream) {
  (void)in_sizes; (void)n_in; (void)out_size; (void)ws_size;
  const float* adj       = (const float*)d_in[0];
  const float* raw_nodes = (const float*)d_in[1];
  const float* proj_w    = (const float*)d_in[2];
  const float* proj_b    = (const float*)d_in[3];
  const float* user_emb  = (const float*)d_in[4];
  const float* item_emb  = (const float*)d_in[5];
  const float* vs        = (const float*)d_in[6];
  const float* alpha_p   = (const float*)d_in[7];
  const float* pgw       = (const float*)d_in[8];
  const float* pgb       = (const float*)d_in[9];
  const float* uaw = (const float*)d_in[10];
  const float* uab = (const float*)d_in[11];
  const float* uw1 = (const float*)d_in[12];
  const float* ub1 = (const float*)d_in[13];
  const float* uw2 = (const float*)d_in[14];
  const float* ub2 = (const float*)d_in[15];
  const float* ulg = (const float*)d_in[16];
  const float* ulb = (const float*)d_in[17];
  const float* iaw = (const float*)d_in[18];
  const float* iab = (const float*)d_in[19];
  const float* iw1 = (const float*)d_in[20];
  const float* ib1 = (const float*)d_in[21];
  const float* iw2 = (const float*)d_in[22];
  const float* ib2 = (const float*)d_in[23];
  const float* ilg = (const float*)d_in[24];
  const float* ilb = (const float*)d_in[25];

  float* w = (float*)d_ws;
  float* pe   = w; w += (size_t)NTOT * DD;
  float* x0   = w; w += (size_t)NTOT * DD;
  float* x1   = w; w += (size_t)NTOT * DD;
  float* x2   = w; w += (size_t)NTOT * DD;
  float* cur  = w; w += (size_t)NTOT * DD;
  float* curg = w; w += (size_t)NTOT * DD;
  float* qkv  = w; w += (size_t)3 * NTOT * DD;
  float* xl   = w; w += (size_t)NTOT * DD;
  float* f2   = w; w += (size_t)NTOT * DD;
  float* t1   = w; w += (size_t)NTOT * DFF2;
  float* dinv = w; w += 4096;
  float* ao   = t1;                          // alias: dead before ffn1 writes t1
  unsigned long long* top8 = (unsigned long long*)qkv;  // NTOT*80 u64 = 3.9 MB

  pe_k<<<(NTOT * 64 + 255) / 256, 256, 0, stream>>>(pe);
  dinv_k<<<II, 256, 0, stream>>>(vs, dinv);
  gemm_blend_k<<<dim3(2, NTOT / 64), 256, 0, stream>>>(
      raw_nodes, proj_w, proj_b, user_emb, item_emb, alpha_p, x0, 1280);

  float* xs[3] = {x0, x1, x2};
  for (int b = 0; b < 2; ++b) {
    const float* prev = xs[b];
    float* outb = xs[b + 1];
    topk_part_k<<<dim3(8, 96), 256, 0, stream>>>(prev, adj, top8);
    topk_merge_k<<<NTOT / 16, 256, 0, stream>>>(top8, adj, prev, cur);
    gemm_sk_k<<<dim3(2, II / 64, 4), 256, 0, stream>>>(
        vs, prev + (size_t)UU * DD, dinv, alpha_p, cur + (size_t)UU * DD, 768);
    gemm_gate_k<<<dim3(2, NTOT / 64), 256, 0, stream>>>(cur, pgw, pgb, pe, curg);
    gemm_qkv2_k<<<dim3(6, NTOT / 64), 256, 0, stream>>>(curg, uaw, iaw, uab, iab, qkv);
    attn_k<<<dim3(NTOT / 32, HH), 256, 0, stream>>>(qkv, ao);
    gemm2_k<false><<<dim3(2, NTOT / 64), 256, 0, stream>>>(
        ao, uaw + 3 * DD * DD, iaw + 3 * DD * DD, uab + 3 * DD, iab + 3 * DD, f2, DD, DD);
    add_ln2_k<<<NTOT, 128, 0, stream>>>(curg, f2, ulg, ulb, ilg, ilb, xl);
    gemm2_k<true ><<<dim3(8, NTOT / 64), 256, 0, stream>>>(
        xl, uw1, iw1, ub1, ib1, t1, DFF2, DD);
    gemm2_k<false><<<dim3(2, NTOT / 64), 256, 0, stream>>>(
        t1, uw2, iw2, ub2, ib2, f2, DD, DFF2);
    add_ln2_k<<<NTOT, 128, 0, stream>>>(xl, f2, ulg + DD, ulb + DD, ilg + DD, ilb + DD, outb);
  }
  final_k<<<(NTOT * DD + 255) / 256, 256, 0, stream>>>(x0, x1, x2, (float*)d_out);
}